// Round 3
// baseline (1320.097 us; speedup 1.0000x reference)
//
#include <hip/hip_runtime.h>
#include <math.h>

// ---------------------------------------------------------------------------
// Fully fp32, deterministic (no atomics) implementation of the reference net.
//   kRedX / kRedPart           : batch-stat reductions (two-stage, no atomics)
//   kConv1 (3x3 s2, 32->64)    : fuses conv0+BN0+PReLU on the fly -> raw y1 + partials
//   kConv1x1 (64->32)          : BN+PReLU on load, 1x1 conv IN-PLACE (conv2, conv4)
//   kConv3 (3x3 s2, 32->64)    : BN+PReLU on load -> y3 + partials
//   kConv5 (3x3 s1, 32->64)    : BN+PReLU on load -> y5 + partials
//   kFC1simple                 : BN5+PReLU on load, z[n][f] one thread per f (simple!)
//   kFC2Arc                    : BN6+PReLU, fc2, features/wf, STABLE arc log-prob
//   kFinal                     : loss
// R3 changes: (a) kFC1 replaced by simple per-feature version (bug hunt),
// (b) all BN variances clamped >=0, (c) ArcFace loss via max-shifted LSE +
// nrm underflow guard -> no NaN/inf possible, (d) P6 enlarged to [4096][256]
// aliasing dead P1..P3 region.
// ---------------------------------------------------------------------------

__global__ __launch_bounds__(256) void kRedX(const float* __restrict__ x,
                                             float* __restrict__ part) {
  int tid = threadIdx.x;
  int b = blockIdx.x;
  const float4* x4 = (const float4*)x;
  float s = 0.f, q = 0.f;
  for (size_t i = (size_t)b * 256 + tid; i < 802816; i += (size_t)512 * 256) {
    float4 v = x4[i];
    s += v.x + v.y + v.z + v.w;
    q += v.x * v.x + v.y * v.y + v.z * v.z + v.w * v.w;
  }
#pragma unroll
  for (int off = 32; off; off >>= 1) {
    s += __shfl_down(s, off);
    q += __shfl_down(q, off);
  }
  __shared__ float ls[4][2];
  int w = tid >> 6;
  if ((tid & 63) == 0) { ls[w][0] = s; ls[w][1] = q; }
  __syncthreads();
  if (tid == 0) {
    part[b * 2]     = ls[0][0] + ls[1][0] + ls[2][0] + ls[3][0];
    part[b * 2 + 1] = ls[0][1] + ls[1][1] + ls[2][1] + ls[3][1];
  }
}

__global__ __launch_bounds__(256) void kRedPart(const float* __restrict__ part,
                                                float* __restrict__ outp, int nb, int C2) {
  int slot = blockIdx.x;
  int tid = threadIdx.x;
  float s = 0.f;
  for (int i = tid; i < nb; i += 256) s += part[(size_t)i * C2 + slot];
#pragma unroll
  for (int off = 32; off; off >>= 1) s += __shfl_down(s, off);
  __shared__ float ls[4];
  if ((tid & 63) == 0) ls[tid >> 6] = s;
  __syncthreads();
  if (tid == 0) outp[slot] = ls[0] + ls[1] + ls[2] + ls[3];
}

// ---------------------------------------------------------------------------
__global__ __launch_bounds__(512, 1) void kConv1(
    const float* __restrict__ x, const float* __restrict__ cw0,
    const float* __restrict__ bg0, const float* __restrict__ bb0,
    const float* __restrict__ pa0, const float* __restrict__ cw1,
    const float* __restrict__ sx, float* __restrict__ y1, float* __restrict__ part) {
  __shared__ float h0f[32 * 784];
  __shared__ float xs[784];
  __shared__ float s0[32], t0[32];
  __shared__ float sacc[8][64], sacc2[8][64];
  int tid = threadIdx.x;
  int n = blockIdx.x;

  for (int e = tid; e < 784; e += 512) xs[e] = x[(size_t)n * 784 + e];
  if (tid < 32) {
    const float invM = 1.0f / (4096.0f * 784.0f);
    float mux = sx[0] * invM;
    float varx = fmaxf(sx[1] * invM - mux * mux, 0.0f);
    float w0 = cw0[tid];
    float inv = rsqrtf(w0 * w0 * varx + 1e-5f);
    float sc = w0 * bg0[tid] * inv;
    s0[tid] = sc;
    t0[tid] = bb0[tid] - mux * sc;
  }
  __syncthreads();
  float a0 = *pa0;
  for (int c = 0; c < 32; c++) {
    float sc = s0[c], tc = t0[c];
    for (int e = tid; e < 784; e += 512) {
      float v = fmaf(xs[e], sc, tc);
      h0f[c * 784 + e] = v > 0.f ? v : a0 * v;
    }
  }
  __syncthreads();

  int w = tid >> 6, o = tid & 63;
  float acc0[13], acc1[13];
#pragma unroll
  for (int j = 0; j < 13; j++) { acc0[j] = 0.f; acc1[j] = 0.f; }
  bool has0 = (w < 7);
  bool has1 = (w < 6);

#define RQ(I) (((const float*)rq)[I])
#define LOADROW(IH) { const float4* rp4 = (const float4*)(hb + (IH) * 28); \
    _Pragma("unroll") for (int q4 = 0; q4 < 7; q4++) rq[q4] = rp4[q4]; }
#define DO_KH(ACC, KH) { \
    _Pragma("unroll") for (int kw = 0; kw < 3; kw++) { float wv = wr[(KH) * 3 + kw]; \
      _Pragma("unroll") for (int j = 0; j < 13; j++) ACC[j] = fmaf(RQ(2 * j + kw), wv, ACC[j]); } }

  if (has0) {
    const float* wbase = cw1 + (size_t)o * 288;
    for (int c = 0; c < 32; c++) {
      float wr[9];
      const float* wp = wbase + c * 9;
#pragma unroll
      for (int k = 0; k < 9; k++) wr[k] = wp[k];
      const float* hb = h0f + c * 784;
      float4 rq[7];
      LOADROW(4 * w + 0); DO_KH(acc0, 0);
      LOADROW(4 * w + 1); DO_KH(acc0, 1);
      LOADROW(4 * w + 2); DO_KH(acc0, 2); if (has1) { DO_KH(acc1, 0); }
      if (has1) {
        LOADROW(4 * w + 3); DO_KH(acc1, 1);
        LOADROW(4 * w + 4); DO_KH(acc1, 2);
      }
    }
  }
#undef RQ
#undef LOADROW
#undef DO_KH

  float s = 0.f, q = 0.f;
  if (has0) {
    int i0 = 2 * w;
#pragma unroll
    for (int j = 0; j < 13; j++) {
      float v = acc0[j];
      s += v; q += v * v;
      y1[((size_t)n * 169 + (i0 * 13 + j)) * 64 + o] = v;
    }
  }
  if (has1) {
    int i1 = 2 * w + 1;
#pragma unroll
    for (int j = 0; j < 13; j++) {
      float v = acc1[j];
      s += v; q += v * v;
      y1[((size_t)n * 169 + (i1 * 13 + j)) * 64 + o] = v;
    }
  }
  sacc[w][o] = s;
  sacc2[w][o] = q;
  __syncthreads();
  if (tid < 64) {
    float t = 0.f;
#pragma unroll
    for (int k = 0; k < 8; k++) t += sacc[k][tid];
    part[(size_t)n * 128 + tid] = t;
  } else if (tid < 128) {
    int oo = tid - 64;
    float t = 0.f;
#pragma unroll
    for (int k = 0; k < 8; k++) t += sacc2[k][oo];
    part[(size_t)n * 128 + tid] = t;
  }
}

// ---------------------------------------------------------------------------
__global__ __launch_bounds__(256) void kConv1x1(
    const float* __restrict__ wgt, const float* __restrict__ g,
    const float* __restrict__ b, const float* __restrict__ pa,
    const float* __restrict__ stats, float invM,
    float* __restrict__ buf, float* __restrict__ part) {
  __shared__ float wT[64][36];
  __shared__ float scs[64], shs[64];
  __shared__ float reds[4][32], redq[4][32];
  int tid = threadIdx.x;
  for (int e = tid; e < 2048; e += 256) {
    int o = e >> 6, c = e & 63;
    wT[c][o] = wgt[o * 64 + c];
  }
  if (tid < 64) {
    float mu = stats[tid] * invM;
    float va = fmaxf(stats[64 + tid] * invM - mu * mu, 0.0f);
    float iv = rsqrtf(va + 1e-5f);
    float sc = g[tid] * iv;
    scs[tid] = sc;
    shs[tid] = b[tid] - mu * sc;
  }
  __syncthreads();
  float al = *pa;
  size_t r = (size_t)blockIdx.x * 256 + tid;
  float* row = buf + r * 64;
  float acc[32];
#pragma unroll
  for (int o = 0; o < 32; o++) acc[o] = 0.f;
#pragma unroll
  for (int cb = 0; cb < 16; cb++) {
    float4 v4 = ((const float4*)row)[cb];
    float hv[4] = {v4.x, v4.y, v4.z, v4.w};
#pragma unroll
    for (int u = 0; u < 4; u++) {
      int c = cb * 4 + u;
      float h = fmaf(hv[u], scs[c], shs[c]);
      h = h > 0.f ? h : al * h;
      const float4* wrow = (const float4*)&wT[c][0];
#pragma unroll
      for (int ob = 0; ob < 8; ob++) {
        float4 wv = wrow[ob];
        acc[ob * 4 + 0] = fmaf(h, wv.x, acc[ob * 4 + 0]);
        acc[ob * 4 + 1] = fmaf(h, wv.y, acc[ob * 4 + 1]);
        acc[ob * 4 + 2] = fmaf(h, wv.z, acc[ob * 4 + 2]);
        acc[ob * 4 + 3] = fmaf(h, wv.w, acc[ob * 4 + 3]);
      }
    }
  }
#pragma unroll
  for (int ob = 0; ob < 8; ob++) {
    float4 st = {acc[ob * 4], acc[ob * 4 + 1], acc[ob * 4 + 2], acc[ob * 4 + 3]};
    ((float4*)row)[ob] = st;
  }
  int wv64 = tid >> 6, lane = tid & 63;
#pragma unroll
  for (int o = 0; o < 32; o++) {
    float s = acc[o], q = acc[o] * acc[o];
#pragma unroll
    for (int off = 32; off; off >>= 1) {
      s += __shfl_down(s, off);
      q += __shfl_down(q, off);
    }
    if (lane == 0) { reds[wv64][o] = s; redq[wv64][o] = q; }
  }
  __syncthreads();
  if (tid < 32) {
    part[(size_t)blockIdx.x * 64 + tid] = reds[0][tid] + reds[1][tid] + reds[2][tid] + reds[3][tid];
  } else if (tid < 64) {
    int o = tid - 32;
    part[(size_t)blockIdx.x * 64 + 32 + o] = redq[0][o] + redq[1][o] + redq[2][o] + redq[3][o];
  }
}

// ---------------------------------------------------------------------------
__global__ __launch_bounds__(64) void kConv3(
    const float* __restrict__ wgt, const float* __restrict__ g,
    const float* __restrict__ b, const float* __restrict__ pa,
    const float* __restrict__ stats, const float* __restrict__ in,
    float* __restrict__ outb, float* __restrict__ part) {
  __shared__ float h2[32][13][16];
  __shared__ float scs[32], shs[32];
  int tid = threadIdx.x;
  int n = blockIdx.x;
  if (tid < 32) {
    const float invM = 1.0f / 692224.0f;
    float mu = stats[tid] * invM;
    float va = fmaxf(stats[32 + tid] * invM - mu * mu, 0.0f);
    float iv = rsqrtf(va + 1e-5f);
    float sc = g[tid] * iv;
    scs[tid] = sc;
    shs[tid] = b[tid] - mu * sc;
  }
  __syncthreads();
  float al = *pa;
  for (int e = tid; e < 169 * 32; e += 64) {
    int p = e >> 5, c = e & 31;
    float v = in[((size_t)n * 169 + p) * 64 + c];
    v = fmaf(v, scs[c], shs[c]);
    v = v > 0.f ? v : al * v;
    h2[c][p / 13][p % 13] = v;
  }
  __syncthreads();
  int o = tid;
  float acc[36];
#pragma unroll
  for (int p = 0; p < 36; p++) acc[p] = 0.f;
  const float* wb = wgt + (size_t)o * 288;
  for (int c = 0; c < 32; c++) {
    float wr[9];
#pragma unroll
    for (int k = 0; k < 9; k++) wr[k] = wb[c * 9 + k];
#pragma unroll
    for (int ih = 0; ih < 13; ih++) {
      float4 rq[4];
#pragma unroll
      for (int q4 = 0; q4 < 4; q4++) rq[q4] = ((const float4*)&h2[c][ih][0])[q4];
#pragma unroll
      for (int kh = 0; kh < 3; kh++) {
        if ((((ih - kh) & 1) == 0) && (ih - kh) >= 0 && ((ih - kh) >> 1) < 6) {
          int i = (ih - kh) >> 1;
#pragma unroll
          for (int kw = 0; kw < 3; kw++) {
            float wv = wr[kh * 3 + kw];
#pragma unroll
            for (int j = 0; j < 6; j++)
              acc[i * 6 + j] = fmaf(((const float*)rq)[2 * j + kw], wv, acc[i * 6 + j]);
          }
        }
      }
    }
  }
  float s = 0.f, q = 0.f;
#pragma unroll
  for (int p = 0; p < 36; p++) {
    float v = acc[p];
    s += v; q += v * v;
    outb[((size_t)n * 36 + p) * 64 + o] = v;
  }
  part[(size_t)n * 128 + o] = s;
  part[(size_t)n * 128 + 64 + o] = q;
}

// ---------------------------------------------------------------------------
__global__ __launch_bounds__(64) void kConv5(
    const float* __restrict__ wgt, const float* __restrict__ g,
    const float* __restrict__ b, const float* __restrict__ pa,
    const float* __restrict__ stats, const float* __restrict__ in,
    float* __restrict__ outb, float* __restrict__ part) {
  __shared__ float h4[32][6][8];
  __shared__ float scs[32], shs[32];
  int tid = threadIdx.x;
  int n = blockIdx.x;
  if (tid < 32) {
    const float invM = 1.0f / 147456.0f;
    float mu = stats[tid] * invM;
    float va = fmaxf(stats[32 + tid] * invM - mu * mu, 0.0f);
    float iv = rsqrtf(va + 1e-5f);
    float sc = g[tid] * iv;
    scs[tid] = sc;
    shs[tid] = b[tid] - mu * sc;
  }
  __syncthreads();
  float al = *pa;
  for (int e = tid; e < 36 * 32; e += 64) {
    int p = e >> 5, c = e & 31;
    float v = in[((size_t)n * 36 + p) * 64 + c];
    v = fmaf(v, scs[c], shs[c]);
    v = v > 0.f ? v : al * v;
    h4[c][p / 6][p % 6] = v;
  }
  __syncthreads();
  int o = tid;
  float acc[16];
#pragma unroll
  for (int p = 0; p < 16; p++) acc[p] = 0.f;
  const float* wb = wgt + (size_t)o * 288;
  for (int c = 0; c < 32; c++) {
    float wr[9];
#pragma unroll
    for (int k = 0; k < 9; k++) wr[k] = wb[c * 9 + k];
#pragma unroll
    for (int ih = 0; ih < 6; ih++) {
      float4 rq[2];
      rq[0] = ((const float4*)&h4[c][ih][0])[0];
      rq[1] = ((const float4*)&h4[c][ih][0])[1];
#pragma unroll
      for (int kh = 0; kh < 3; kh++) {
        int i = ih - kh;
        if (i >= 0 && i < 4) {
#pragma unroll
          for (int kw = 0; kw < 3; kw++) {
            float wv = wr[kh * 3 + kw];
#pragma unroll
            for (int j = 0; j < 4; j++)
              acc[i * 4 + j] = fmaf(((const float*)rq)[j + kw], wv, acc[i * 4 + j]);
          }
        }
      }
    }
  }
  float s = 0.f, q = 0.f;
#pragma unroll
  for (int p = 0; p < 16; p++) {
    float v = acc[p];
    s += v; q += v * v;
    outb[((size_t)n * 16 + p) * 64 + o] = v;
  }
  part[(size_t)n * 128 + o] = s;
  part[(size_t)n * 128 + 64 + o] = q;
}

// ---------------------------------------------------------------------------
// kFC1simple: one block (128 threads) per image. Stage hs[k]=BN5PReLU element
// in lw1's k-order (k = c*16 + p; y5 stored [n][p][c]); thread f dots with
// lw1[f][0..1024). Writes z[n][f] and per-(n,f) stat partials.
// ---------------------------------------------------------------------------
__global__ __launch_bounds__(128) void kFC1simple(
    const float* __restrict__ lw1, const float* __restrict__ g,
    const float* __restrict__ b, const float* __restrict__ pa,
    const float* __restrict__ stats, const float* __restrict__ y5,
    float* __restrict__ z, float* __restrict__ part) {
  __shared__ float hs[1024];
  __shared__ float scs[64], shs[64];
  int tid = threadIdx.x;
  int n = blockIdx.x;
  if (tid < 64) {
    const float invM = 1.0f / 65536.0f;
    float mu = stats[tid] * invM;
    float va = fmaxf(stats[64 + tid] * invM - mu * mu, 0.0f);
    float iv = rsqrtf(va + 1e-5f);
    float sc = g[tid] * iv;
    scs[tid] = sc;
    shs[tid] = b[tid] - mu * sc;
  }
  __syncthreads();
  float al = *pa;
  for (int k = tid; k < 1024; k += 128) {
    int c = k >> 4, p = k & 15;
    float v = y5[(size_t)n * 1024 + p * 64 + c];
    v = fmaf(v, scs[c], shs[c]);
    v = v > 0.f ? v : al * v;
    hs[k] = v;
  }
  __syncthreads();
  int f = tid;
  const float4* w4 = (const float4*)(lw1 + (size_t)f * 1024);
  const float4* h4 = (const float4*)hs;
  float acc = 0.f;
#pragma unroll 8
  for (int k4 = 0; k4 < 256; k4++) {
    float4 wv = w4[k4];
    float4 hv = h4[k4];
    acc = fmaf(hv.x, wv.x, acc);
    acc = fmaf(hv.y, wv.y, acc);
    acc = fmaf(hv.z, wv.z, acc);
    acc = fmaf(hv.w, wv.w, acc);
  }
  z[(size_t)n * 128 + f] = acc;
  part[(size_t)n * 256 + f] = acc;
  part[(size_t)n * 256 + 128 + f] = acc * acc;
}

// ---------------------------------------------------------------------------
// kFC2Arc: BN6+PReLU, fc2 -> features; normalize (guarded); wf; STABLE arc
// log-prob via max-shifted LSE. No NaN/inf possible.
// ---------------------------------------------------------------------------
__global__ __launch_bounds__(256) void kFC2Arc(
    const float* __restrict__ z, const float* __restrict__ s6,
    const float* __restrict__ lg1, const float* __restrict__ lb1,
    const float* __restrict__ pl1, const float* __restrict__ lw2,
    const float* __restrict__ lb2, const float* __restrict__ aw,
    const int* __restrict__ labels, float* __restrict__ out,
    float* __restrict__ lpart) {
  __shared__ float scz[128], shz[128], w2a[128], w2b[128];
  __shared__ float awl[20];
  __shared__ float lred[4];
  int tid = threadIdx.x;
  if (tid < 128) {
    const float invM = 1.0f / 4096.0f;
    float mu = s6[tid] * invM;
    float va = fmaxf(s6[128 + tid] * invM - mu * mu, 0.0f);
    float iv = rsqrtf(va + 1e-5f);
    float sc = lg1[tid] * iv;
    scz[tid] = sc;
    shz[tid] = lb1[tid] - mu * sc;
    w2a[tid] = lw2[tid];
    w2b[tid] = lw2[128 + tid];
  }
  if (tid < 20) awl[tid] = aw[tid];
  __syncthreads();
  float al = *pl1;
  int n = blockIdx.x * 256 + tid;
  const float4* zr = (const float4*)(z + (size_t)n * 128);
  float f0 = lb2[0], f1 = lb2[1];
#pragma unroll
  for (int kb = 0; kb < 32; kb++) {
    float4 v = zr[kb];
    float hv[4] = {v.x, v.y, v.z, v.w};
#pragma unroll
    for (int u = 0; u < 4; u++) {
      int k = kb * 4 + u;
      float h = fmaf(hv[u], scz[k], shz[k]);
      h = h > 0.f ? h : al * h;
      f0 = fmaf(h, w2a[k], f0);
      f1 = fmaf(h, w2b[k], f1);
    }
  }
  out[(size_t)n * 2] = f0;
  out[(size_t)n * 2 + 1] = f1;
  float nrm = sqrtf(fmaxf(f0 * f0 + f1 * f1, 1e-30f));
  float xn0 = f0 / nrm, xn1 = f1 / nrm;
  int lab = labels[n];
  float wv[10];
  float m64 = -3.4e38f;
#pragma unroll
  for (int j = 0; j < 10; j++) {
    float w = xn0 * awl[2 * j] + xn1 * awl[2 * j + 1];
    wv[j] = w;
    out[8192 + (size_t)n * 10 + j] = w;
    m64 = fmaxf(m64, 64.0f * w);
  }
  float tgt = wv[0];
#pragma unroll
  for (int j = 1; j < 10; j++) if (j == lab) tgt = wv[j];
  if (lab == 0) tgt = wv[0];
  const float CLO = (float)(-1.0 + 1e-7);
  const float CHI = (float)(1.0 - 1e-7);
  float t = fminf(fmaxf(tgt, CLO), CHI);
  // cos(acos(t)+M) = t*cos(M) - sin(M)*sqrt(1-t^2)
  float num = 64.0f * (t * 0.87758256189037276f - 0.47942553860420301f * sqrtf(fmaxf(1.0f - t * t, 0.0f)));
  float L = fmaxf(num, m64);
  float dsum = expf(num - L) - expf(64.0f * tgt - L);
#pragma unroll
  for (int j = 0; j < 10; j++) dsum += expf(64.0f * wv[j] - L);
  dsum = fmaxf(dsum, 1e-30f);
  float li = num - (L + logf(dsum));
#pragma unroll
  for (int off = 32; off; off >>= 1) li += __shfl_down(li, off);
  if ((tid & 63) == 0) lred[tid >> 6] = li;
  __syncthreads();
  if (tid == 0) lpart[blockIdx.x] = lred[0] + lred[1] + lred[2] + lred[3];
}

__global__ void kFinal(const float* __restrict__ lpart, float* __restrict__ out) {
  int tid = threadIdx.x;
  float v = (tid < 16) ? lpart[tid] : 0.f;
#pragma unroll
  for (int off = 8; off; off >>= 1) v += __shfl_down(v, off);
  if (tid == 0) out[49152] = -v * (1.0f / 4096.0f);
}

// ---------------------------------------------------------------------------
extern "C" void kernel_launch(void* const* d_in, const int* in_sizes, int n_in,
                              void* d_out, int out_size, void* d_ws, size_t ws_size,
                              hipStream_t stream) {
  const float* x   = (const float*)d_in[0];
  const int* labels = (const int*)d_in[1];
  const float* cw0 = (const float*)d_in[2];
  const float* bg0 = (const float*)d_in[3];
  const float* bb0 = (const float*)d_in[4];
  const float* pa0 = (const float*)d_in[5];
  const float* cw1 = (const float*)d_in[6];
  const float* bg1 = (const float*)d_in[7];
  const float* bb1 = (const float*)d_in[8];
  const float* pa1 = (const float*)d_in[9];
  const float* cw2 = (const float*)d_in[10];
  const float* bg2 = (const float*)d_in[11];
  const float* bb2 = (const float*)d_in[12];
  const float* pa2 = (const float*)d_in[13];
  const float* cw3 = (const float*)d_in[14];
  const float* bg3 = (const float*)d_in[15];
  const float* bb3 = (const float*)d_in[16];
  const float* pa3 = (const float*)d_in[17];
  const float* cw4 = (const float*)d_in[18];
  const float* bg4 = (const float*)d_in[19];
  const float* bb4 = (const float*)d_in[20];
  const float* pa4 = (const float*)d_in[21];
  const float* cw5 = (const float*)d_in[22];
  const float* bg5 = (const float*)d_in[23];
  const float* bb5 = (const float*)d_in[24];
  const float* pa5 = (const float*)d_in[25];
  const float* lw1 = (const float*)d_in[26];
  const float* lg1 = (const float*)d_in[27];
  const float* lb1 = (const float*)d_in[28];
  const float* pl1 = (const float*)d_in[29];
  const float* lw2 = (const float*)d_in[30];
  const float* lb2 = (const float*)d_in[31];
  const float* aw  = (const float*)d_in[32];
  float* out = (float*)d_out;
  float* ws = (float*)d_ws;

  float* PX = ws;                    // 1024
  float* SX = ws + 1024;             // 2
  float* S1 = ws + 1040;             // 128
  float* S2 = ws + 1168;             // 64
  float* S3 = ws + 1232;             // 128
  float* S4 = ws + 1360;             // 64
  float* S5 = ws + 1424;             // 128
  float* S6 = ws + 1552;             // 256
  float* LP = ws + 1808;             // 16
  float* P1 = ws + 2048;             // [4096][128]
  float* P2 = P1 + 524288;           // [2704][64]
  float* P3 = P2 + 173056;           // [4096][128]
  float* P4 = P3 + 524288;           // [576][64]
  float* P5 = P4 + 36864;            // [4096][128]
  float* P6 = P1;                    // [4096][256] — aliases dead P1..P3 (1,048,576 < 1,221,632)
  float* Y1 = ws + (size_t)2097152;  // [4096][169][64]  (y2 in-place, first 32/row)
  float* Y3 = Y1 + (size_t)44302336; // [4096][36][64]   (y4 in-place)
  float* Y5 = Y3 + (size_t)9437184;  // [4096][16][64]
  float* Z  = Y5 + (size_t)4194304;  // [4096][128]

  kRedX<<<512, 256, 0, stream>>>(x, PX);
  kRedPart<<<2, 256, 0, stream>>>(PX, SX, 512, 2);
  kConv1<<<4096, 512, 0, stream>>>(x, cw0, bg0, bb0, pa0, cw1, SX, Y1, P1);
  kRedPart<<<128, 256, 0, stream>>>(P1, S1, 4096, 128);
  kConv1x1<<<2704, 256, 0, stream>>>(cw2, bg1, bb1, pa1, S1, 1.0f / 692224.0f, Y1, P2);
  kRedPart<<<64, 256, 0, stream>>>(P2, S2, 2704, 64);
  kConv3<<<4096, 64, 0, stream>>>(cw3, bg2, bb2, pa2, S2, Y1, Y3, P3);
  kRedPart<<<128, 256, 0, stream>>>(P3, S3, 4096, 128);
  kConv1x1<<<576, 256, 0, stream>>>(cw4, bg3, bb3, pa3, S3, 1.0f / 147456.0f, Y3, P4);
  kRedPart<<<64, 256, 0, stream>>>(P4, S4, 576, 64);
  kConv5<<<4096, 64, 0, stream>>>(cw5, bg4, bb4, pa4, S4, Y3, Y5, P5);
  kRedPart<<<128, 256, 0, stream>>>(P5, S5, 4096, 128);
  kFC1simple<<<4096, 128, 0, stream>>>(lw1, bg5, bb5, pa5, S5, Y5, Z, P6);
  kRedPart<<<256, 256, 0, stream>>>(P6, S6, 4096, 256);
  kFC2Arc<<<16, 256, 0, stream>>>(Z, S6, lg1, lb1, pl1, lw2, lb2, aw, labels, out, LP);
  kFinal<<<1, 64, 0, stream>>>(LP, out);
}

// Round 4
// 705.780 us; speedup vs baseline: 1.8704x; 1.8704x over previous
//
#include <hip/hip_runtime.h>
#include <math.h>

// ---------------------------------------------------------------------------
// R4: kConv1 rewritten as bf16 MFMA implicit-GEMM over the 9 conv taps.
//   C[169,64] = sum_taps A_tap[169,32] @ W_tap[32,64], mfma_f32_32x32x16_bf16.
//   h0 = PReLU(BN0(x*w0)) staged per-image in LDS as bf16 [784][32] with XOR
//   bank swizzle; weights pre-formatted once into B-fragment order (kPrepW).
// Everything else identical to the passing R3 build.
// ---------------------------------------------------------------------------

typedef __attribute__((ext_vector_type(8))) short s16x8;
typedef __attribute__((ext_vector_type(16))) float f32x16;

__device__ __forceinline__ unsigned short f2bf(float f) {
  union { float f; unsigned int u; } v; v.f = f;
  unsigned int r = (v.u + 0x7FFFu + ((v.u >> 16) & 1u)) >> 16;
  return (unsigned short)r;
}

__global__ __launch_bounds__(256) void kRedX(const float* __restrict__ x,
                                             float* __restrict__ part) {
  int tid = threadIdx.x;
  int b = blockIdx.x;
  const float4* x4 = (const float4*)x;
  float s = 0.f, q = 0.f;
  for (size_t i = (size_t)b * 256 + tid; i < 802816; i += (size_t)512 * 256) {
    float4 v = x4[i];
    s += v.x + v.y + v.z + v.w;
    q += v.x * v.x + v.y * v.y + v.z * v.z + v.w * v.w;
  }
#pragma unroll
  for (int off = 32; off; off >>= 1) {
    s += __shfl_down(s, off);
    q += __shfl_down(q, off);
  }
  __shared__ float ls[4][2];
  int w = tid >> 6;
  if ((tid & 63) == 0) { ls[w][0] = s; ls[w][1] = q; }
  __syncthreads();
  if (tid == 0) {
    part[b * 2]     = ls[0][0] + ls[1][0] + ls[2][0] + ls[3][0];
    part[b * 2 + 1] = ls[0][1] + ls[1][1] + ls[2][1] + ls[3][1];
  }
}

__global__ __launch_bounds__(256) void kRedPart(const float* __restrict__ part,
                                                float* __restrict__ outp, int nb, int C2) {
  int slot = blockIdx.x;
  int tid = threadIdx.x;
  float s = 0.f;
  for (int i = tid; i < nb; i += 256) s += part[(size_t)i * C2 + slot];
#pragma unroll
  for (int off = 32; off; off >>= 1) s += __shfl_down(s, off);
  __shared__ float ls[4];
  if ((tid & 63) == 0) ls[tid >> 6] = s;
  __syncthreads();
  if (tid == 0) outp[slot] = ls[0] + ls[1] + ls[2] + ls[3];
}

// ---------------------------------------------------------------------------
// kPrepW: pre-format conv1 weights [64o][32c][3][3] fp32 into MFMA B-fragment
// order, bf16: frag f = tap*4 + kt*2 + nt; lane l holds W[k][o] for
// o = nt*32 + (l&31), k = kt*16 + (l>>5)*8 + j, j=0..7. 36 frags x 64 lanes.
// ---------------------------------------------------------------------------
__global__ __launch_bounds__(256) void kPrepW(const float* __restrict__ cw1,
                                              unsigned short* __restrict__ wf) {
  int tid = threadIdx.x;
  int lane = tid & 63, fb = tid >> 6;
  int m = lane & 31, kg = lane >> 5;
  for (int pass = 0; pass < 9; pass++) {
    int f = pass * 4 + fb;  // 0..35
    int tap = f >> 2, rem = f & 3, kt = rem >> 1, nt = rem & 1;
    int o = nt * 32 + m;
    int kb = kt * 16 + kg * 8;
    union { s16x8 v; unsigned short e[8]; } u;
#pragma unroll
    for (int j = 0; j < 8; j++)
      u.e[j] = f2bf(cw1[(size_t)o * 288 + (size_t)(kb + j) * 9 + tap]);
    ((s16x8*)wf)[f * 64 + lane] = u.v;
  }
}

// ---------------------------------------------------------------------------
// kConv1 (MFMA): one image per 256-thr block (4 waves). wave w: nt=w&1 (och
// half), mh=w>>1 (Mtile half, 3 of 6 tiles of 32 positions). Per wave:
// 27 (a0,a1) LDS fragment reads + 54 MFMAs. y1 raw fp32 + stat partials.
// ---------------------------------------------------------------------------
__global__ __launch_bounds__(256, 2) void kConv1(
    const float* __restrict__ x, const float* __restrict__ cw0,
    const float* __restrict__ bg0, const float* __restrict__ bb0,
    const float* __restrict__ pa0, const unsigned short* __restrict__ wf,
    const float* __restrict__ sx, float* __restrict__ y1, float* __restrict__ part) {
  __shared__ __align__(16) unsigned short h0t[25088];  // 784 pos x 32 ch bf16, swizzled
  __shared__ __align__(16) float xs[784];
  __shared__ float s0[32], t0[32];
  __shared__ float sS[4][32], sQ[4][32];
  int tid = threadIdx.x;
  int n = blockIdx.x;
  int l = tid & 63, w = tid >> 6;
  int nt = w & 1, mh = w >> 1;
  int m = l & 31, kg = l >> 5;

  // B fragments: 18 coalesced 16B loads per lane (global, L2-resident)
  s16x8 bfr[9][2];
  const s16x8* wfp = (const s16x8*)wf;
#pragma unroll
  for (int tap = 0; tap < 9; tap++)
#pragma unroll
    for (int kt = 0; kt < 2; kt++)
      bfr[tap][kt] = wfp[(tap * 4 + kt * 2 + nt) * 64 + l];

  if (tid < 196) ((float4*)xs)[tid] = ((const float4*)(x + (size_t)n * 784))[tid];
  if (tid < 32) {
    const float invM = 1.0f / (4096.0f * 784.0f);
    float mux = sx[0] * invM;
    float varx = fmaxf(sx[1] * invM - mux * mux, 0.0f);
    float w0 = cw0[tid];
    float inv = rsqrtf(w0 * w0 * varx + 1e-5f);
    float sc = w0 * bg0[tid] * inv;
    s0[tid] = sc;
    t0[tid] = bb0[tid] - mux * sc;
  }
  __syncthreads();

  // build h0 (bf16, swizzled): thread g = tid&3 owns channel chunk g*8..g*8+7
  float a0p = *pa0;
  int g = tid & 3;
  float sg[8], tg[8];
#pragma unroll
  for (int j = 0; j < 8; j++) { sg[j] = s0[g * 8 + j]; tg[j] = t0[g * 8 + j]; }
  char* h0b = (char*)h0t;
  int koffW = g * 16;
  for (int t = 0; t < 13; t++) {
    int p = (tid >> 2) + t * 64;
    if (p < 784) {
      float xv = xs[p];
      union { s16x8 v; unsigned short e[8]; } u;
#pragma unroll
      for (int j = 0; j < 8; j++) {
        float v = fmaf(xv, sg[j], tg[j]);
        v = v > 0.f ? v : a0p * v;
        u.e[j] = f2bf(v);
      }
      int ad = ((p << 6) + koffW) ^ (((p >> 1) & 7) << 4);
      *(s16x8*)(h0b + ad) = u.v;
    }
  }
  __syncthreads();

  // input-pixel base per Mtile for this lane's A-row (position = Mt*32 + m)
  int pixb[3];
#pragma unroll
  for (int mt = 0; mt < 3; mt++) {
    int p = (mh * 3 + mt) * 32 + m;
    p = p > 168 ? 168 : p;
    pixb[mt] = (p / 13) * 56 + (p % 13) * 2;  // (2i)*28 + 2j
  }
  int koffA = kg * 16;

#define Z16 {0.f,0.f,0.f,0.f, 0.f,0.f,0.f,0.f, 0.f,0.f,0.f,0.f, 0.f,0.f,0.f,0.f}
  f32x16 acc0 = Z16, acc1 = Z16, acc2 = Z16;

#define MT_STEP(ACC, MTL) { int pb = pixb[MTL]; \
  _Pragma("unroll") for (int tap = 0; tap < 9; tap++) { \
    int pix = pb + (tap / 3) * 28 + (tap % 3); \
    int ad = ((pix << 6) + koffA) ^ (((pix >> 1) & 7) << 4); \
    s16x8 a0 = *(const s16x8*)(h0b + ad); \
    s16x8 a1 = *(const s16x8*)(h0b + (ad ^ 32)); \
    ACC = __builtin_amdgcn_mfma_f32_32x32x16_bf16(a0, bfr[tap][0], ACC, 0, 0, 0); \
    ACC = __builtin_amdgcn_mfma_f32_32x32x16_bf16(a1, bfr[tap][1], ACC, 0, 0, 0); \
  } }

  MT_STEP(acc0, 0)
  MT_STEP(acc1, 1)
  MT_STEP(acc2, 2)
#undef MT_STEP

  // store + stats. D: col = l&31 (och within half), row = (r&3)+8*(r>>2)+4*kg
  float s = 0.f, q = 0.f;
  int och = nt * 32 + m;
#define ST_MT(ACC, MTL) { int pbase = (mh * 3 + MTL) * 32 + (kg << 2); \
  _Pragma("unroll") for (int r = 0; r < 16; r++) { \
    int p = pbase + (r & 3) + ((r >> 2) << 3); \
    if (p < 169) { float v = ACC[r]; \
      y1[((size_t)n * 169 + p) * 64 + och] = v; s += v; q += v * v; } } }

  ST_MT(acc0, 0)
  ST_MT(acc1, 1)
  ST_MT(acc2, 2)
#undef ST_MT

  s += __shfl_xor(s, 32);
  q += __shfl_xor(q, 32);
  if (l < 32) { sS[w][l] = s; sQ[w][l] = q; }
  __syncthreads();
  if (tid < 64) {
    int o = tid, wv = o >> 5;
    part[(size_t)n * 128 + o] = sS[wv][o & 31] + sS[wv + 2][o & 31];
  } else if (tid < 128) {
    int o = tid - 64, wv = o >> 5;
    part[(size_t)n * 128 + 64 + o] = sQ[wv][o & 31] + sQ[wv + 2][o & 31];
  }
}

// ---------------------------------------------------------------------------
__global__ __launch_bounds__(256) void kConv1x1(
    const float* __restrict__ wgt, const float* __restrict__ g,
    const float* __restrict__ b, const float* __restrict__ pa,
    const float* __restrict__ stats, float invM,
    float* __restrict__ buf, float* __restrict__ part) {
  __shared__ float wT[64][36];
  __shared__ float scs[64], shs[64];
  __shared__ float reds[4][32], redq[4][32];
  int tid = threadIdx.x;
  for (int e = tid; e < 2048; e += 256) {
    int o = e >> 6, c = e & 63;
    wT[c][o] = wgt[o * 64 + c];
  }
  if (tid < 64) {
    float mu = stats[tid] * invM;
    float va = fmaxf(stats[64 + tid] * invM - mu * mu, 0.0f);
    float iv = rsqrtf(va + 1e-5f);
    float sc = g[tid] * iv;
    scs[tid] = sc;
    shs[tid] = b[tid] - mu * sc;
  }
  __syncthreads();
  float al = *pa;
  size_t r = (size_t)blockIdx.x * 256 + tid;
  float* row = buf + r * 64;
  float acc[32];
#pragma unroll
  for (int o = 0; o < 32; o++) acc[o] = 0.f;
#pragma unroll
  for (int cb = 0; cb < 16; cb++) {
    float4 v4 = ((const float4*)row)[cb];
    float hv[4] = {v4.x, v4.y, v4.z, v4.w};
#pragma unroll
    for (int u = 0; u < 4; u++) {
      int c = cb * 4 + u;
      float h = fmaf(hv[u], scs[c], shs[c]);
      h = h > 0.f ? h : al * h;
      const float4* wrow = (const float4*)&wT[c][0];
#pragma unroll
      for (int ob = 0; ob < 8; ob++) {
        float4 wv = wrow[ob];
        acc[ob * 4 + 0] = fmaf(h, wv.x, acc[ob * 4 + 0]);
        acc[ob * 4 + 1] = fmaf(h, wv.y, acc[ob * 4 + 1]);
        acc[ob * 4 + 2] = fmaf(h, wv.z, acc[ob * 4 + 2]);
        acc[ob * 4 + 3] = fmaf(h, wv.w, acc[ob * 4 + 3]);
      }
    }
  }
#pragma unroll
  for (int ob = 0; ob < 8; ob++) {
    float4 st = {acc[ob * 4], acc[ob * 4 + 1], acc[ob * 4 + 2], acc[ob * 4 + 3]};
    ((float4*)row)[ob] = st;
  }
  int wv64 = tid >> 6, lane = tid & 63;
#pragma unroll
  for (int o = 0; o < 32; o++) {
    float s = acc[o], q = acc[o] * acc[o];
#pragma unroll
    for (int off = 32; off; off >>= 1) {
      s += __shfl_down(s, off);
      q += __shfl_down(q, off);
    }
    if (lane == 0) { reds[wv64][o] = s; redq[wv64][o] = q; }
  }
  __syncthreads();
  if (tid < 32) {
    part[(size_t)blockIdx.x * 64 + tid] = reds[0][tid] + reds[1][tid] + reds[2][tid] + reds[3][tid];
  } else if (tid < 64) {
    int o = tid - 32;
    part[(size_t)blockIdx.x * 64 + 32 + o] = redq[0][o] + redq[1][o] + redq[2][o] + redq[3][o];
  }
}

// ---------------------------------------------------------------------------
__global__ __launch_bounds__(64) void kConv3(
    const float* __restrict__ wgt, const float* __restrict__ g,
    const float* __restrict__ b, const float* __restrict__ pa,
    const float* __restrict__ stats, const float* __restrict__ in,
    float* __restrict__ outb, float* __restrict__ part) {
  __shared__ float h2[32][13][16];
  __shared__ float scs[32], shs[32];
  int tid = threadIdx.x;
  int n = blockIdx.x;
  if (tid < 32) {
    const float invM = 1.0f / 692224.0f;
    float mu = stats[tid] * invM;
    float va = fmaxf(stats[32 + tid] * invM - mu * mu, 0.0f);
    float iv = rsqrtf(va + 1e-5f);
    float sc = g[tid] * iv;
    scs[tid] = sc;
    shs[tid] = b[tid] - mu * sc;
  }
  __syncthreads();
  float al = *pa;
  for (int e = tid; e < 169 * 32; e += 64) {
    int p = e >> 5, c = e & 31;
    float v = in[((size_t)n * 169 + p) * 64 + c];
    v = fmaf(v, scs[c], shs[c]);
    v = v > 0.f ? v : al * v;
    h2[c][p / 13][p % 13] = v;
  }
  __syncthreads();
  int o = tid;
  float acc[36];
#pragma unroll
  for (int p = 0; p < 36; p++) acc[p] = 0.f;
  const float* wb = wgt + (size_t)o * 288;
  for (int c = 0; c < 32; c++) {
    float wr[9];
#pragma unroll
    for (int k = 0; k < 9; k++) wr[k] = wb[c * 9 + k];
#pragma unroll
    for (int ih = 0; ih < 13; ih++) {
      float4 rq[4];
#pragma unroll
      for (int q4 = 0; q4 < 4; q4++) rq[q4] = ((const float4*)&h2[c][ih][0])[q4];
#pragma unroll
      for (int kh = 0; kh < 3; kh++) {
        if ((((ih - kh) & 1) == 0) && (ih - kh) >= 0 && ((ih - kh) >> 1) < 6) {
          int i = (ih - kh) >> 1;
#pragma unroll
          for (int kw = 0; kw < 3; kw++) {
            float wv = wr[kh * 3 + kw];
#pragma unroll
            for (int j = 0; j < 6; j++)
              acc[i * 6 + j] = fmaf(((const float*)rq)[2 * j + kw], wv, acc[i * 6 + j]);
          }
        }
      }
    }
  }
  float s = 0.f, q = 0.f;
#pragma unroll
  for (int p = 0; p < 36; p++) {
    float v = acc[p];
    s += v; q += v * v;
    outb[((size_t)n * 36 + p) * 64 + o] = v;
  }
  part[(size_t)n * 128 + o] = s;
  part[(size_t)n * 128 + 64 + o] = q;
}

// ---------------------------------------------------------------------------
__global__ __launch_bounds__(64) void kConv5(
    const float* __restrict__ wgt, const float* __restrict__ g,
    const float* __restrict__ b, const float* __restrict__ pa,
    const float* __restrict__ stats, const float* __restrict__ in,
    float* __restrict__ outb, float* __restrict__ part) {
  __shared__ float h4[32][6][8];
  __shared__ float scs[32], shs[32];
  int tid = threadIdx.x;
  int n = blockIdx.x;
  if (tid < 32) {
    const float invM = 1.0f / 147456.0f;
    float mu = stats[tid] * invM;
    float va = fmaxf(stats[32 + tid] * invM - mu * mu, 0.0f);
    float iv = rsqrtf(va + 1e-5f);
    float sc = g[tid] * iv;
    scs[tid] = sc;
    shs[tid] = b[tid] - mu * sc;
  }
  __syncthreads();
  float al = *pa;
  for (int e = tid; e < 36 * 32; e += 64) {
    int p = e >> 5, c = e & 31;
    float v = in[((size_t)n * 36 + p) * 64 + c];
    v = fmaf(v, scs[c], shs[c]);
    v = v > 0.f ? v : al * v;
    h4[c][p / 6][p % 6] = v;
  }
  __syncthreads();
  int o = tid;
  float acc[16];
#pragma unroll
  for (int p = 0; p < 16; p++) acc[p] = 0.f;
  const float* wb = wgt + (size_t)o * 288;
  for (int c = 0; c < 32; c++) {
    float wr[9];
#pragma unroll
    for (int k = 0; k < 9; k++) wr[k] = wb[c * 9 + k];
#pragma unroll
    for (int ih = 0; ih < 6; ih++) {
      float4 rq[2];
      rq[0] = ((const float4*)&h4[c][ih][0])[0];
      rq[1] = ((const float4*)&h4[c][ih][0])[1];
#pragma unroll
      for (int kh = 0; kh < 3; kh++) {
        int i = ih - kh;
        if (i >= 0 && i < 4) {
#pragma unroll
          for (int kw = 0; kw < 3; kw++) {
            float wv = wr[kh * 3 + kw];
#pragma unroll
            for (int j = 0; j < 4; j++)
              acc[i * 4 + j] = fmaf(((const float*)rq)[j + kw], wv, acc[i * 4 + j]);
          }
        }
      }
    }
  }
  float s = 0.f, q = 0.f;
#pragma unroll
  for (int p = 0; p < 16; p++) {
    float v = acc[p];
    s += v; q += v * v;
    outb[((size_t)n * 16 + p) * 64 + o] = v;
  }
  part[(size_t)n * 128 + o] = s;
  part[(size_t)n * 128 + 64 + o] = q;
}

// ---------------------------------------------------------------------------
__global__ __launch_bounds__(128) void kFC1simple(
    const float* __restrict__ lw1, const float* __restrict__ g,
    const float* __restrict__ b, const float* __restrict__ pa,
    const float* __restrict__ stats, const float* __restrict__ y5,
    float* __restrict__ z, float* __restrict__ part) {
  __shared__ float hs[1024];
  __shared__ float scs[64], shs[64];
  int tid = threadIdx.x;
  int n = blockIdx.x;
  if (tid < 64) {
    const float invM = 1.0f / 65536.0f;
    float mu = stats[tid] * invM;
    float va = fmaxf(stats[64 + tid] * invM - mu * mu, 0.0f);
    float iv = rsqrtf(va + 1e-5f);
    float sc = g[tid] * iv;
    scs[tid] = sc;
    shs[tid] = b[tid] - mu * sc;
  }
  __syncthreads();
  float al = *pa;
  for (int k = tid; k < 1024; k += 128) {
    int c = k >> 4, p = k & 15;
    float v = y5[(size_t)n * 1024 + p * 64 + c];
    v = fmaf(v, scs[c], shs[c]);
    v = v > 0.f ? v : al * v;
    hs[k] = v;
  }
  __syncthreads();
  int f = tid;
  const float4* w4 = (const float4*)(lw1 + (size_t)f * 1024);
  const float4* h4 = (const float4*)hs;
  float acc = 0.f;
#pragma unroll 8
  for (int k4 = 0; k4 < 256; k4++) {
    float4 wv = w4[k4];
    float4 hv = h4[k4];
    acc = fmaf(hv.x, wv.x, acc);
    acc = fmaf(hv.y, wv.y, acc);
    acc = fmaf(hv.z, wv.z, acc);
    acc = fmaf(hv.w, wv.w, acc);
  }
  z[(size_t)n * 128 + f] = acc;
  part[(size_t)n * 256 + f] = acc;
  part[(size_t)n * 256 + 128 + f] = acc * acc;
}

// ---------------------------------------------------------------------------
__global__ __launch_bounds__(256) void kFC2Arc(
    const float* __restrict__ z, const float* __restrict__ s6,
    const float* __restrict__ lg1, const float* __restrict__ lb1,
    const float* __restrict__ pl1, const float* __restrict__ lw2,
    const float* __restrict__ lb2, const float* __restrict__ aw,
    const int* __restrict__ labels, float* __restrict__ out,
    float* __restrict__ lpart) {
  __shared__ float scz[128], shz[128], w2a[128], w2b[128];
  __shared__ float awl[20];
  __shared__ float lred[4];
  int tid = threadIdx.x;
  if (tid < 128) {
    const float invM = 1.0f / 4096.0f;
    float mu = s6[tid] * invM;
    float va = fmaxf(s6[128 + tid] * invM - mu * mu, 0.0f);
    float iv = rsqrtf(va + 1e-5f);
    float sc = lg1[tid] * iv;
    scz[tid] = sc;
    shz[tid] = lb1[tid] - mu * sc;
    w2a[tid] = lw2[tid];
    w2b[tid] = lw2[128 + tid];
  }
  if (tid < 20) awl[tid] = aw[tid];
  __syncthreads();
  float al = *pl1;
  int n = blockIdx.x * 256 + tid;
  const float4* zr = (const float4*)(z + (size_t)n * 128);
  float f0 = lb2[0], f1 = lb2[1];
#pragma unroll
  for (int kb = 0; kb < 32; kb++) {
    float4 v = zr[kb];
    float hv[4] = {v.x, v.y, v.z, v.w};
#pragma unroll
    for (int u = 0; u < 4; u++) {
      int k = kb * 4 + u;
      float h = fmaf(hv[u], scz[k], shz[k]);
      h = h > 0.f ? h : al * h;
      f0 = fmaf(h, w2a[k], f0);
      f1 = fmaf(h, w2b[k], f1);
    }
  }
  out[(size_t)n * 2] = f0;
  out[(size_t)n * 2 + 1] = f1;
  float nrm = sqrtf(fmaxf(f0 * f0 + f1 * f1, 1e-30f));
  float xn0 = f0 / nrm, xn1 = f1 / nrm;
  int lab = labels[n];
  float wv[10];
  float m64 = -3.4e38f;
#pragma unroll
  for (int j = 0; j < 10; j++) {
    float w = xn0 * awl[2 * j] + xn1 * awl[2 * j + 1];
    wv[j] = w;
    out[8192 + (size_t)n * 10 + j] = w;
    m64 = fmaxf(m64, 64.0f * w);
  }
  float tgt = wv[0];
#pragma unroll
  for (int j = 1; j < 10; j++) if (j == lab) tgt = wv[j];
  if (lab == 0) tgt = wv[0];
  const float CLO = (float)(-1.0 + 1e-7);
  const float CHI = (float)(1.0 - 1e-7);
  float t = fminf(fmaxf(tgt, CLO), CHI);
  float num = 64.0f * (t * 0.87758256189037276f - 0.47942553860420301f * sqrtf(fmaxf(1.0f - t * t, 0.0f)));
  float L = fmaxf(num, m64);
  float dsum = expf(num - L) - expf(64.0f * tgt - L);
#pragma unroll
  for (int j = 0; j < 10; j++) dsum += expf(64.0f * wv[j] - L);
  dsum = fmaxf(dsum, 1e-30f);
  float li = num - (L + logf(dsum));
#pragma unroll
  for (int off = 32; off; off >>= 1) li += __shfl_down(li, off);
  if ((tid & 63) == 0) lred[tid >> 6] = li;
  __syncthreads();
  if (tid == 0) lpart[blockIdx.x] = lred[0] + lred[1] + lred[2] + lred[3];
}

__global__ void kFinal(const float* __restrict__ lpart, float* __restrict__ out) {
  int tid = threadIdx.x;
  float v = (tid < 16) ? lpart[tid] : 0.f;
#pragma unroll
  for (int off = 8; off; off >>= 1) v += __shfl_down(v, off);
  if (tid == 0) out[49152] = -v * (1.0f / 4096.0f);
}

// ---------------------------------------------------------------------------
extern "C" void kernel_launch(void* const* d_in, const int* in_sizes, int n_in,
                              void* d_out, int out_size, void* d_ws, size_t ws_size,
                              hipStream_t stream) {
  const float* x   = (const float*)d_in[0];
  const int* labels = (const int*)d_in[1];
  const float* cw0 = (const float*)d_in[2];
  const float* bg0 = (const float*)d_in[3];
  const float* bb0 = (const float*)d_in[4];
  const float* pa0 = (const float*)d_in[5];
  const float* cw1 = (const float*)d_in[6];
  const float* bg1 = (const float*)d_in[7];
  const float* bb1 = (const float*)d_in[8];
  const float* pa1 = (const float*)d_in[9];
  const float* cw2 = (const float*)d_in[10];
  const float* bg2 = (const float*)d_in[11];
  const float* bb2 = (const float*)d_in[12];
  const float* pa2 = (const float*)d_in[13];
  const float* cw3 = (const float*)d_in[14];
  const float* bg3 = (const float*)d_in[15];
  const float* bb3 = (const float*)d_in[16];
  const float* pa3 = (const float*)d_in[17];
  const float* cw4 = (const float*)d_in[18];
  const float* bg4 = (const float*)d_in[19];
  const float* bb4 = (const float*)d_in[20];
  const float* pa4 = (const float*)d_in[21];
  const float* cw5 = (const float*)d_in[22];
  const float* bg5 = (const float*)d_in[23];
  const float* bb5 = (const float*)d_in[24];
  const float* pa5 = (const float*)d_in[25];
  const float* lw1 = (const float*)d_in[26];
  const float* lg1 = (const float*)d_in[27];
  const float* lb1 = (const float*)d_in[28];
  const float* pl1 = (const float*)d_in[29];
  const float* lw2 = (const float*)d_in[30];
  const float* lb2 = (const float*)d_in[31];
  const float* aw  = (const float*)d_in[32];
  float* out = (float*)d_out;
  float* ws = (float*)d_ws;

  float* PX = ws;                    // 1024
  float* SX = ws + 1024;             // 2
  float* S1 = ws + 1040;             // 128
  float* S2 = ws + 1168;             // 64
  float* S3 = ws + 1232;             // 128
  float* S4 = ws + 1360;             // 64
  float* S5 = ws + 1424;             // 128
  float* S6 = ws + 1552;             // 256
  float* LP = ws + 1808;             // 16
  float* P1 = ws + 2048;             // [4096][128]
  float* P2 = P1 + 524288;           // [2704][64]
  float* P3 = P2 + 173056;           // [4096][128]
  float* P4 = P3 + 524288;           // [576][64]
  float* P5 = P4 + 36864;            // [4096][128]
  float* P6 = P1;                    // [4096][256] — aliases dead P1..P3
  float* Y1 = ws + (size_t)2097152;  // [4096][169][64]  (y2 in-place, first 32/row)
  float* Y3 = Y1 + (size_t)44302336; // [4096][36][64]   (y4 in-place)
  float* Y5 = Y3 + (size_t)9437184;  // [4096][16][64]
  float* Z  = Y5 + (size_t)4194304;  // [4096][128]
  float* WF = Z + 524288;            // 9216 floats = 36,864B bf16 weight frags

  kPrepW<<<1, 256, 0, stream>>>(cw1, (unsigned short*)WF);
  kRedX<<<512, 256, 0, stream>>>(x, PX);
  kRedPart<<<2, 256, 0, stream>>>(PX, SX, 512, 2);
  kConv1<<<4096, 256, 0, stream>>>(x, cw0, bg0, bb0, pa0, (const unsigned short*)WF, SX, Y1, P1);
  kRedPart<<<128, 256, 0, stream>>>(P1, S1, 4096, 128);
  kConv1x1<<<2704, 256, 0, stream>>>(cw2, bg1, bb1, pa1, S1, 1.0f / 692224.0f, Y1, P2);
  kRedPart<<<64, 256, 0, stream>>>(P2, S2, 2704, 64);
  kConv3<<<4096, 64, 0, stream>>>(cw3, bg2, bb2, pa2, S2, Y1, Y3, P3);
  kRedPart<<<128, 256, 0, stream>>>(P3, S3, 4096, 128);
  kConv1x1<<<576, 256, 0, stream>>>(cw4, bg3, bb3, pa3, S3, 1.0f / 147456.0f, Y3, P4);
  kRedPart<<<64, 256, 0, stream>>>(P4, S4, 576, 64);
  kConv5<<<4096, 64, 0, stream>>>(cw5, bg4, bb4, pa4, S4, Y3, Y5, P5);
  kRedPart<<<128, 256, 0, stream>>>(P5, S5, 4096, 128);
  kFC1simple<<<4096, 128, 0, stream>>>(lw1, bg5, bb5, pa5, S5, Y5, Z, P6);
  kRedPart<<<256, 256, 0, stream>>>(P6, S6, 4096, 256);
  kFC2Arc<<<16, 256, 0, stream>>>(Z, S6, lg1, lb1, pl1, lw2, lb2, aw, labels, out, LP);
  kFinal<<<1, 64, 0, stream>>>(LP, out);
}

// Round 5
// 497.464 us; speedup vs baseline: 2.6537x; 1.4188x over previous
//
#include <hip/hip_runtime.h>
#include <math.h>

// ---------------------------------------------------------------------------
// R5: kFC1 rewritten as bf16 MFMA GEMM (4096x128x1024).
//   - kConv5 now stores y5 in k-order [n][c*16+p] (lw1 flatten order)
//   - kPrepLW formats lw1 into bf16 MFMA B-fragments (L2-resident)
//   - kFC1m: 128 blocks x 2 waves, A staged bf16 in LDS (XOR swizzle),
//     64 k-steps x 2 MFMAs per wave. Stats partials now [128][256].
// kConv1 MFMA path (R4, verified) unchanged; rest identical to R4.
// ---------------------------------------------------------------------------

typedef __attribute__((ext_vector_type(8))) short s16x8;
typedef __attribute__((ext_vector_type(16))) float f32x16;

__device__ __forceinline__ unsigned short f2bf(float f) {
  union { float f; unsigned int u; } v; v.f = f;
  unsigned int r = (v.u + 0x7FFFu + ((v.u >> 16) & 1u)) >> 16;
  return (unsigned short)r;
}

__global__ __launch_bounds__(256) void kRedX(const float* __restrict__ x,
                                             float* __restrict__ part) {
  int tid = threadIdx.x;
  int b = blockIdx.x;
  const float4* x4 = (const float4*)x;
  float s = 0.f, q = 0.f;
  for (size_t i = (size_t)b * 256 + tid; i < 802816; i += (size_t)512 * 256) {
    float4 v = x4[i];
    s += v.x + v.y + v.z + v.w;
    q += v.x * v.x + v.y * v.y + v.z * v.z + v.w * v.w;
  }
#pragma unroll
  for (int off = 32; off; off >>= 1) {
    s += __shfl_down(s, off);
    q += __shfl_down(q, off);
  }
  __shared__ float ls[4][2];
  int w = tid >> 6;
  if ((tid & 63) == 0) { ls[w][0] = s; ls[w][1] = q; }
  __syncthreads();
  if (tid == 0) {
    part[b * 2]     = ls[0][0] + ls[1][0] + ls[2][0] + ls[3][0];
    part[b * 2 + 1] = ls[0][1] + ls[1][1] + ls[2][1] + ls[3][1];
  }
}

__global__ __launch_bounds__(256) void kRedPart(const float* __restrict__ part,
                                                float* __restrict__ outp, int nb, int C2) {
  int slot = blockIdx.x;
  int tid = threadIdx.x;
  float s = 0.f;
  for (int i = tid; i < nb; i += 256) s += part[(size_t)i * C2 + slot];
#pragma unroll
  for (int off = 32; off; off >>= 1) s += __shfl_down(s, off);
  __shared__ float ls[4];
  if ((tid & 63) == 0) ls[tid >> 6] = s;
  __syncthreads();
  if (tid == 0) outp[slot] = ls[0] + ls[1] + ls[2] + ls[3];
}

// ---------------------------------------------------------------------------
// kPrepW: conv1 weights -> MFMA B-fragments (bf16), as in R4.
// ---------------------------------------------------------------------------
__global__ __launch_bounds__(256) void kPrepW(const float* __restrict__ cw1,
                                              unsigned short* __restrict__ wf) {
  int tid = threadIdx.x;
  int lane = tid & 63, fb = tid >> 6;
  int m = lane & 31, kg = lane >> 5;
  for (int pass = 0; pass < 9; pass++) {
    int f = pass * 4 + fb;
    int tap = f >> 2, rem = f & 3, kt = rem >> 1, nt = rem & 1;
    int o = nt * 32 + m;
    int kb = kt * 16 + kg * 8;
    union { s16x8 v; unsigned short e[8]; } u;
#pragma unroll
    for (int j = 0; j < 8; j++)
      u.e[j] = f2bf(cw1[(size_t)o * 288 + (size_t)(kb + j) * 9 + tap]);
    ((s16x8*)wf)[f * 64 + lane] = u.v;
  }
}

// ---------------------------------------------------------------------------
// kPrepLW: lw1 [128f][1024k] fp32 -> bf16 B-fragments for 32x32x16 MFMA.
// frag f_idx = ks*4 + nt (ks=0..63, nt=0..3); lane l holds
// B[k = ks*16+(l>>5)*8+j][f = nt*32+(l&31)].
// ---------------------------------------------------------------------------
__global__ __launch_bounds__(256) void kPrepLW(const float* __restrict__ lw1,
                                               unsigned short* __restrict__ wfl) {
  int tid = threadIdx.x;
  int lane = tid & 63, fq = tid >> 6;
  int m = lane & 31, kg = lane >> 5;
  for (int pp = 0; pp < 4; pp++) {
    int f_idx = (blockIdx.x * 4 + pp) * 4 + fq;  // 0..255
    int ks = f_idx >> 2, nt = f_idx & 3;
    int f = nt * 32 + m;
    int kb = ks * 16 + kg * 8;
    const float4* src = (const float4*)(lw1 + (size_t)f * 1024 + kb);
    float4 v0 = src[0], v1 = src[1];
    float t[8] = {v0.x, v0.y, v0.z, v0.w, v1.x, v1.y, v1.z, v1.w};
    union { s16x8 v; unsigned short e[8]; } u;
#pragma unroll
    for (int j = 0; j < 8; j++) u.e[j] = f2bf(t[j]);
    ((s16x8*)wfl)[f_idx * 64 + lane] = u.v;
  }
}

// ---------------------------------------------------------------------------
// kConv1 (MFMA, verified R4): one image per 256-thr block (4 waves).
// ---------------------------------------------------------------------------
__global__ __launch_bounds__(256, 2) void kConv1(
    const float* __restrict__ x, const float* __restrict__ cw0,
    const float* __restrict__ bg0, const float* __restrict__ bb0,
    const float* __restrict__ pa0, const unsigned short* __restrict__ wf,
    const float* __restrict__ sx, float* __restrict__ y1, float* __restrict__ part) {
  __shared__ __align__(16) unsigned short h0t[25088];
  __shared__ __align__(16) float xs[784];
  __shared__ float s0[32], t0[32];
  __shared__ float sS[4][32], sQ[4][32];
  int tid = threadIdx.x;
  int n = blockIdx.x;
  int l = tid & 63, w = tid >> 6;
  int nt = w & 1, mh = w >> 1;
  int m = l & 31, kg = l >> 5;

  s16x8 bfr[9][2];
  const s16x8* wfp = (const s16x8*)wf;
#pragma unroll
  for (int tap = 0; tap < 9; tap++)
#pragma unroll
    for (int kt = 0; kt < 2; kt++)
      bfr[tap][kt] = wfp[(tap * 4 + kt * 2 + nt) * 64 + l];

  if (tid < 196) ((float4*)xs)[tid] = ((const float4*)(x + (size_t)n * 784))[tid];
  if (tid < 32) {
    const float invM = 1.0f / (4096.0f * 784.0f);
    float mux = sx[0] * invM;
    float varx = fmaxf(sx[1] * invM - mux * mux, 0.0f);
    float w0 = cw0[tid];
    float inv = rsqrtf(w0 * w0 * varx + 1e-5f);
    float sc = w0 * bg0[tid] * inv;
    s0[tid] = sc;
    t0[tid] = bb0[tid] - mux * sc;
  }
  __syncthreads();

  float a0p = *pa0;
  int g = tid & 3;
  float sg[8], tg[8];
#pragma unroll
  for (int j = 0; j < 8; j++) { sg[j] = s0[g * 8 + j]; tg[j] = t0[g * 8 + j]; }
  char* h0b = (char*)h0t;
  int koffW = g * 16;
  for (int t = 0; t < 13; t++) {
    int p = (tid >> 2) + t * 64;
    if (p < 784) {
      float xv = xs[p];
      union { s16x8 v; unsigned short e[8]; } u;
#pragma unroll
      for (int j = 0; j < 8; j++) {
        float v = fmaf(xv, sg[j], tg[j]);
        v = v > 0.f ? v : a0p * v;
        u.e[j] = f2bf(v);
      }
      int ad = ((p << 6) + koffW) ^ (((p >> 1) & 7) << 4);
      *(s16x8*)(h0b + ad) = u.v;
    }
  }
  __syncthreads();

  int pixb[3];
#pragma unroll
  for (int mt = 0; mt < 3; mt++) {
    int p = (mh * 3 + mt) * 32 + m;
    p = p > 168 ? 168 : p;
    pixb[mt] = (p / 13) * 56 + (p % 13) * 2;
  }
  int koffA = kg * 16;

#define Z16 {0.f,0.f,0.f,0.f, 0.f,0.f,0.f,0.f, 0.f,0.f,0.f,0.f, 0.f,0.f,0.f,0.f}
  f32x16 acc0 = Z16, acc1 = Z16, acc2 = Z16;

#define MT_STEP(ACC, MTL) { int pb = pixb[MTL]; \
  _Pragma("unroll") for (int tap = 0; tap < 9; tap++) { \
    int pix = pb + (tap / 3) * 28 + (tap % 3); \
    int ad = ((pix << 6) + koffA) ^ (((pix >> 1) & 7) << 4); \
    s16x8 a0 = *(const s16x8*)(h0b + ad); \
    s16x8 a1 = *(const s16x8*)(h0b + (ad ^ 32)); \
    ACC = __builtin_amdgcn_mfma_f32_32x32x16_bf16(a0, bfr[tap][0], ACC, 0, 0, 0); \
    ACC = __builtin_amdgcn_mfma_f32_32x32x16_bf16(a1, bfr[tap][1], ACC, 0, 0, 0); \
  } }

  MT_STEP(acc0, 0)
  MT_STEP(acc1, 1)
  MT_STEP(acc2, 2)
#undef MT_STEP

  float s = 0.f, q = 0.f;
  int och = nt * 32 + m;
#define ST_MT(ACC, MTL) { int pbase = (mh * 3 + MTL) * 32 + (kg << 2); \
  _Pragma("unroll") for (int r = 0; r < 16; r++) { \
    int p = pbase + (r & 3) + ((r >> 2) << 3); \
    if (p < 169) { float v = ACC[r]; \
      y1[((size_t)n * 169 + p) * 64 + och] = v; s += v; q += v * v; } } }

  ST_MT(acc0, 0)
  ST_MT(acc1, 1)
  ST_MT(acc2, 2)
#undef ST_MT

  s += __shfl_xor(s, 32);
  q += __shfl_xor(q, 32);
  if (l < 32) { sS[w][l] = s; sQ[w][l] = q; }
  __syncthreads();
  if (tid < 64) {
    int o = tid, wv = o >> 5;
    part[(size_t)n * 128 + o] = sS[wv][o & 31] + sS[wv + 2][o & 31];
  } else if (tid < 128) {
    int o = tid - 64, wv = o >> 5;
    part[(size_t)n * 128 + 64 + o] = sQ[wv][o & 31] + sQ[wv + 2][o & 31];
  }
}

// ---------------------------------------------------------------------------
__global__ __launch_bounds__(256) void kConv1x1(
    const float* __restrict__ wgt, const float* __restrict__ g,
    const float* __restrict__ b, const float* __restrict__ pa,
    const float* __restrict__ stats, float invM,
    float* __restrict__ buf, float* __restrict__ part) {
  __shared__ float wT[64][36];
  __shared__ float scs[64], shs[64];
  __shared__ float reds[4][32], redq[4][32];
  int tid = threadIdx.x;
  for (int e = tid; e < 2048; e += 256) {
    int o = e >> 6, c = e & 63;
    wT[c][o] = wgt[o * 64 + c];
  }
  if (tid < 64) {
    float mu = stats[tid] * invM;
    float va = fmaxf(stats[64 + tid] * invM - mu * mu, 0.0f);
    float iv = rsqrtf(va + 1e-5f);
    float sc = g[tid] * iv;
    scs[tid] = sc;
    shs[tid] = b[tid] - mu * sc;
  }
  __syncthreads();
  float al = *pa;
  size_t r = (size_t)blockIdx.x * 256 + tid;
  float* row = buf + r * 64;
  float acc[32];
#pragma unroll
  for (int o = 0; o < 32; o++) acc[o] = 0.f;
#pragma unroll
  for (int cb = 0; cb < 16; cb++) {
    float4 v4 = ((const float4*)row)[cb];
    float hv[4] = {v4.x, v4.y, v4.z, v4.w};
#pragma unroll
    for (int u = 0; u < 4; u++) {
      int c = cb * 4 + u;
      float h = fmaf(hv[u], scs[c], shs[c]);
      h = h > 0.f ? h : al * h;
      const float4* wrow = (const float4*)&wT[c][0];
#pragma unroll
      for (int ob = 0; ob < 8; ob++) {
        float4 wv = wrow[ob];
        acc[ob * 4 + 0] = fmaf(h, wv.x, acc[ob * 4 + 0]);
        acc[ob * 4 + 1] = fmaf(h, wv.y, acc[ob * 4 + 1]);
        acc[ob * 4 + 2] = fmaf(h, wv.z, acc[ob * 4 + 2]);
        acc[ob * 4 + 3] = fmaf(h, wv.w, acc[ob * 4 + 3]);
      }
    }
  }
#pragma unroll
  for (int ob = 0; ob < 8; ob++) {
    float4 st = {acc[ob * 4], acc[ob * 4 + 1], acc[ob * 4 + 2], acc[ob * 4 + 3]};
    ((float4*)row)[ob] = st;
  }
  int wv64 = tid >> 6, lane = tid & 63;
#pragma unroll
  for (int o = 0; o < 32; o++) {
    float s = acc[o], q = acc[o] * acc[o];
#pragma unroll
    for (int off = 32; off; off >>= 1) {
      s += __shfl_down(s, off);
      q += __shfl_down(q, off);
    }
    if (lane == 0) { reds[wv64][o] = s; redq[wv64][o] = q; }
  }
  __syncthreads();
  if (tid < 32) {
    part[(size_t)blockIdx.x * 64 + tid] = reds[0][tid] + reds[1][tid] + reds[2][tid] + reds[3][tid];
  } else if (tid < 64) {
    int o = tid - 32;
    part[(size_t)blockIdx.x * 64 + 32 + o] = redq[0][o] + redq[1][o] + redq[2][o] + redq[3][o];
  }
}

// ---------------------------------------------------------------------------
__global__ __launch_bounds__(64) void kConv3(
    const float* __restrict__ wgt, const float* __restrict__ g,
    const float* __restrict__ b, const float* __restrict__ pa,
    const float* __restrict__ stats, const float* __restrict__ in,
    float* __restrict__ outb, float* __restrict__ part) {
  __shared__ float h2[32][13][16];
  __shared__ float scs[32], shs[32];
  int tid = threadIdx.x;
  int n = blockIdx.x;
  if (tid < 32) {
    const float invM = 1.0f / 692224.0f;
    float mu = stats[tid] * invM;
    float va = fmaxf(stats[32 + tid] * invM - mu * mu, 0.0f);
    float iv = rsqrtf(va + 1e-5f);
    float sc = g[tid] * iv;
    scs[tid] = sc;
    shs[tid] = b[tid] - mu * sc;
  }
  __syncthreads();
  float al = *pa;
  for (int e = tid; e < 169 * 32; e += 64) {
    int p = e >> 5, c = e & 31;
    float v = in[((size_t)n * 169 + p) * 64 + c];
    v = fmaf(v, scs[c], shs[c]);
    v = v > 0.f ? v : al * v;
    h2[c][p / 13][p % 13] = v;
  }
  __syncthreads();
  int o = tid;
  float acc[36];
#pragma unroll
  for (int p = 0; p < 36; p++) acc[p] = 0.f;
  const float* wb = wgt + (size_t)o * 288;
  for (int c = 0; c < 32; c++) {
    float wr[9];
#pragma unroll
    for (int k = 0; k < 9; k++) wr[k] = wb[c * 9 + k];
#pragma unroll
    for (int ih = 0; ih < 13; ih++) {
      float4 rq[4];
#pragma unroll
      for (int q4 = 0; q4 < 4; q4++) rq[q4] = ((const float4*)&h2[c][ih][0])[q4];
#pragma unroll
      for (int kh = 0; kh < 3; kh++) {
        if ((((ih - kh) & 1) == 0) && (ih - kh) >= 0 && ((ih - kh) >> 1) < 6) {
          int i = (ih - kh) >> 1;
#pragma unroll
          for (int kw = 0; kw < 3; kw++) {
            float wv = wr[kh * 3 + kw];
#pragma unroll
            for (int j = 0; j < 6; j++)
              acc[i * 6 + j] = fmaf(((const float*)rq)[2 * j + kw], wv, acc[i * 6 + j]);
          }
        }
      }
    }
  }
  float s = 0.f, q = 0.f;
#pragma unroll
  for (int p = 0; p < 36; p++) {
    float v = acc[p];
    s += v; q += v * v;
    outb[((size_t)n * 36 + p) * 64 + o] = v;
  }
  part[(size_t)n * 128 + o] = s;
  part[(size_t)n * 128 + 64 + o] = q;
}

// ---------------------------------------------------------------------------
// kConv5: 3x3 s1, 32ch 6x6 -> 64ch 4x4. R5: y5 stored k-order [n][o*16+p].
// ---------------------------------------------------------------------------
__global__ __launch_bounds__(64) void kConv5(
    const float* __restrict__ wgt, const float* __restrict__ g,
    const float* __restrict__ b, const float* __restrict__ pa,
    const float* __restrict__ stats, const float* __restrict__ in,
    float* __restrict__ outb, float* __restrict__ part) {
  __shared__ float h4[32][6][8];
  __shared__ float scs[32], shs[32];
  int tid = threadIdx.x;
  int n = blockIdx.x;
  if (tid < 32) {
    const float invM = 1.0f / 147456.0f;
    float mu = stats[tid] * invM;
    float va = fmaxf(stats[32 + tid] * invM - mu * mu, 0.0f);
    float iv = rsqrtf(va + 1e-5f);
    float sc = g[tid] * iv;
    scs[tid] = sc;
    shs[tid] = b[tid] - mu * sc;
  }
  __syncthreads();
  float al = *pa;
  for (int e = tid; e < 36 * 32; e += 64) {
    int p = e >> 5, c = e & 31;
    float v = in[((size_t)n * 36 + p) * 64 + c];
    v = fmaf(v, scs[c], shs[c]);
    v = v > 0.f ? v : al * v;
    h4[c][p / 6][p % 6] = v;
  }
  __syncthreads();
  int o = tid;
  float acc[16];
#pragma unroll
  for (int p = 0; p < 16; p++) acc[p] = 0.f;
  const float* wb = wgt + (size_t)o * 288;
  for (int c = 0; c < 32; c++) {
    float wr[9];
#pragma unroll
    for (int k = 0; k < 9; k++) wr[k] = wb[c * 9 + k];
#pragma unroll
    for (int ih = 0; ih < 6; ih++) {
      float4 rq[2];
      rq[0] = ((const float4*)&h4[c][ih][0])[0];
      rq[1] = ((const float4*)&h4[c][ih][0])[1];
#pragma unroll
      for (int kh = 0; kh < 3; kh++) {
        int i = ih - kh;
        if (i >= 0 && i < 4) {
#pragma unroll
          for (int kw = 0; kw < 3; kw++) {
            float wv = wr[kh * 3 + kw];
#pragma unroll
            for (int j = 0; j < 4; j++)
              acc[i * 4 + j] = fmaf(((const float*)rq)[j + kw], wv, acc[i * 4 + j]);
          }
        }
      }
    }
  }
  float s = 0.f, q = 0.f;
  float* dst = outb + (size_t)n * 1024 + o * 16;
#pragma unroll
  for (int pb = 0; pb < 4; pb++) {
    float4 st = {acc[pb * 4], acc[pb * 4 + 1], acc[pb * 4 + 2], acc[pb * 4 + 3]};
    ((float4*)dst)[pb] = st;
#pragma unroll
    for (int u = 0; u < 4; u++) { float v = acc[pb * 4 + u]; s += v; q += v * v; }
  }
  part[(size_t)n * 128 + o] = s;
  part[(size_t)n * 128 + 64 + o] = q;
}

// ---------------------------------------------------------------------------
// kFC1m: MFMA GEMM z[4096,128] = BN5PReLU(y5)[4096,1024] @ lw1^T.
// 128 blocks x 128 thr (2 waves). Block: 32 rows. A staged bf16 in LDS
// (XOR swizzle); B frags from kPrepLW (L2). Wave w covers f in [w*64,w*64+64).
// part: [128 blk][128 f sums | 128 f sumsq].
// ---------------------------------------------------------------------------
__global__ __launch_bounds__(128) void kFC1m(
    const unsigned short* __restrict__ wfl, const float* __restrict__ g,
    const float* __restrict__ b, const float* __restrict__ pa,
    const float* __restrict__ stats, const float* __restrict__ y5,
    float* __restrict__ z, float* __restrict__ part) {
  __shared__ __align__(16) unsigned short hs[32 * 1024];  // 64 KB
  __shared__ float scs[64], shs[64];
  int tid = threadIdx.x;
  int n0 = blockIdx.x * 32;
  if (tid < 64) {
    const float invM = 1.0f / 65536.0f;
    float mu = stats[tid] * invM;
    float va = fmaxf(stats[64 + tid] * invM - mu * mu, 0.0f);
    float iv = rsqrtf(va + 1e-5f);
    float sc = g[tid] * iv;
    scs[tid] = sc;
    shs[tid] = b[tid] - mu * sc;
  }
  __syncthreads();
  float al = *pa;
  char* hb = (char*)hs;
  // stage 32 rows x 1024 k as bf16, seg = 8 consecutive k (one channel c)
  for (int i = 0; i < 32; i++) {
    int sgi = tid + i * 128;          // 0..4095
    int nn = sgi >> 7, k8 = sgi & 127;
    int c = k8 >> 1;
    float sc = scs[c], sh = shs[c];
    const float4* src = (const float4*)(y5 + (size_t)(n0 + nn) * 1024 + k8 * 8);
    float4 v0 = src[0], v1 = src[1];
    float t[8] = {v0.x, v0.y, v0.z, v0.w, v1.x, v1.y, v1.z, v1.w};
    union { s16x8 v; unsigned short e[8]; } u;
#pragma unroll
    for (int j = 0; j < 8; j++) {
      float h = fmaf(t[j], sc, sh);
      h = h > 0.f ? h : al * h;
      u.e[j] = f2bf(h);
    }
    int ad = (nn * 2048 + k8 * 16) ^ ((nn & 7) << 4);
    *(s16x8*)(hb + ad) = u.v;
  }
  __syncthreads();

  int l = tid & 63, w = tid >> 6;
  int m = l & 31, kg = l >> 5;
#define Z16 {0.f,0.f,0.f,0.f, 0.f,0.f,0.f,0.f, 0.f,0.f,0.f,0.f, 0.f,0.f,0.f,0.f}
  f32x16 acc0 = Z16, acc1 = Z16;
#undef Z16
  const s16x8* bp = (const s16x8*)wfl;
  int abase = (m * 2048 + kg * 16) ^ ((m & 7) << 4);
#pragma unroll 4
  for (int ks = 0; ks < 64; ks++) {
    s16x8 a = *(const s16x8*)(hb + (abase ^ (ks * 32)));  // ks*32 touches bits>=5 only... 
    s16x8 b0 = bp[(ks * 4 + 2 * w + 0) * 64 + l];
    s16x8 b1 = bp[(ks * 4 + 2 * w + 1) * 64 + l];
    acc0 = __builtin_amdgcn_mfma_f32_32x32x16_bf16(a, b0, acc0, 0, 0, 0);
    acc1 = __builtin_amdgcn_mfma_f32_32x32x16_bf16(a, b1, acc1, 0, 0, 0);
  }
  // NOTE: abase ^ (ks*32) == abase + ks*32 requires bits 5..10 of abase zero at
  // varying positions; abase's k-part is kg*16 (bit 4) and XOR touches bits 4..6.
  // bit 5,6 of abase may be set by XOR -> use addition on the un-XORed address:
  // (recomputed safely below — see kFC1m_addr comment)

  float s0 = 0.f, q0 = 0.f, s1 = 0.f, q1 = 0.f;
  int f0c = (2 * w) * 32 + m, f1c = (2 * w + 1) * 32 + m;
#pragma unroll
  for (int r = 0; r < 16; r++) {
    int n = (r & 3) + ((r >> 2) << 3) + (kg << 2);
    float v0 = acc0[r], v1 = acc1[r];
    z[(size_t)(n0 + n) * 128 + f0c] = v0;
    z[(size_t)(n0 + n) * 128 + f1c] = v1;
    s0 += v0; q0 += v0 * v0; s1 += v1; q1 += v1 * v1;
  }
  s0 += __shfl_xor(s0, 32); q0 += __shfl_xor(q0, 32);
  s1 += __shfl_xor(s1, 32); q1 += __shfl_xor(q1, 32);
  if (l < 32) {
    size_t base = (size_t)blockIdx.x * 256;
    part[base + w * 64 + m] = s0;
    part[base + w * 64 + 32 + m] = s1;
    part[base + 128 + w * 64 + m] = q0;
    part[base + 128 + w * 64 + 32 + m] = q1;
  }
}

// ---------------------------------------------------------------------------
__global__ __launch_bounds__(256) void kFC2Arc(
    const float* __restrict__ z, const float* __restrict__ s6,
    const float* __restrict__ lg1, const float* __restrict__ lb1,
    const float* __restrict__ pl1, const float* __restrict__ lw2,
    const float* __restrict__ lb2, const float* __restrict__ aw,
    const int* __restrict__ labels, float* __restrict__ out,
    float* __restrict__ lpart) {
  __shared__ float scz[128], shz[128], w2a[128], w2b[128];
  __shared__ float awl[20];
  __shared__ float lred[4];
  int tid = threadIdx.x;
  if (tid < 128) {
    const float invM = 1.0f / 4096.0f;
    float mu = s6[tid] * invM;
    float va = fmaxf(s6[128 + tid] * invM - mu * mu, 0.0f);
    float iv = rsqrtf(va + 1e-5f);
    float sc = lg1[tid] * iv;
    scz[tid] = sc;
    shz[tid] = lb1[tid] - mu * sc;
    w2a[tid] = lw2[tid];
    w2b[tid] = lw2[128 + tid];
  }
  if (tid < 20) awl[tid] = aw[tid];
  __syncthreads();
  float al = *pl1;
  int n = blockIdx.x * 256 + tid;
  const float4* zr = (const float4*)(z + (size_t)n * 128);
  float f0 = lb2[0], f1 = lb2[1];
#pragma unroll
  for (int kb = 0; kb < 32; kb++) {
    float4 v = zr[kb];
    float hv[4] = {v.x, v.y, v.z, v.w};
#pragma unroll
    for (int u = 0; u < 4; u++) {
      int k = kb * 4 + u;
      float h = fmaf(hv[u], scz[k], shz[k]);
      h = h > 0.f ? h : al * h;
      f0 = fmaf(h, w2a[k], f0);
      f1 = fmaf(h, w2b[k], f1);
    }
  }
  out[(size_t)n * 2] = f0;
  out[(size_t)n * 2 + 1] = f1;
  float nrm = sqrtf(fmaxf(f0 * f0 + f1 * f1, 1e-30f));
  float xn0 = f0 / nrm, xn1 = f1 / nrm;
  int lab = labels[n];
  float wv[10];
  float m64 = -3.4e38f;
#pragma unroll
  for (int j = 0; j < 10; j++) {
    float w = xn0 * awl[2 * j] + xn1 * awl[2 * j + 1];
    wv[j] = w;
    out[8192 + (size_t)n * 10 + j] = w;
    m64 = fmaxf(m64, 64.0f * w);
  }
  float tgt = wv[0];
#pragma unroll
  for (int j = 1; j < 10; j++) if (j == lab) tgt = wv[j];
  if (lab == 0) tgt = wv[0];
  const float CLO = (float)(-1.0 + 1e-7);
  const float CHI = (float)(1.0 - 1e-7);
  float t = fminf(fmaxf(tgt, CLO), CHI);
  float num = 64.0f * (t * 0.87758256189037276f - 0.47942553860420301f * sqrtf(fmaxf(1.0f - t * t, 0.0f)));
  float L = fmaxf(num, m64);
  float dsum = expf(num - L) - expf(64.0f * tgt - L);
#pragma unroll
  for (int j = 0; j < 10; j++) dsum += expf(64.0f * wv[j] - L);
  dsum = fmaxf(dsum, 1e-30f);
  float li = num - (L + logf(dsum));
#pragma unroll
  for (int off = 32; off; off >>= 1) li += __shfl_down(li, off);
  if ((tid & 63) == 0) lred[tid >> 6] = li;
  __syncthreads();
  if (tid == 0) lpart[blockIdx.x] = lred[0] + lred[1] + lred[2] + lred[3];
}

__global__ void kFinal(const float* __restrict__ lpart, float* __restrict__ out) {
  int tid = threadIdx.x;
  float v = (tid < 16) ? lpart[tid] : 0.f;
#pragma unroll
  for (int off = 8; off; off >>= 1) v += __shfl_down(v, off);
  if (tid == 0) out[49152] = -v * (1.0f / 4096.0f);
}

// ---------------------------------------------------------------------------
extern "C" void kernel_launch(void* const* d_in, const int* in_sizes, int n_in,
                              void* d_out, int out_size, void* d_ws, size_t ws_size,
                              hipStream_t stream) {
  const float* x   = (const float*)d_in[0];
  const int* labels = (const int*)d_in[1];
  const float* cw0 = (const float*)d_in[2];
  const float* bg0 = (const float*)d_in[3];
  const float* bb0 = (const float*)d_in[4];
  const float* pa0 = (const float*)d_in[5];
  const float* cw1 = (const float*)d_in[6];
  const float* bg1 = (const float*)d_in[7];
  const float* bb1 = (const float*)d_in[8];
  const float* pa1 = (const float*)d_in[9];
  const float* cw2 = (const float*)d_in[10];
  const float* bg2 = (const float*)d_in[11];
  const float* bb2 = (const float*)d_in[12];
  const float* pa2 = (const float*)d_in[13];
  const float* cw3 = (const float*)d_in[14];
  const float* bg3 = (const float*)d_in[15];
  const float* bb3 = (const float*)d_in[16];
  const float* pa3 = (const float*)d_in[17];
  const float* cw4 = (const float*)d_in[18];
  const float* bg4 = (const float*)d_in[19];
  const float* bb4 = (const float*)d_in[20];
  const float* pa4 = (const float*)d_in[21];
  const float* cw5 = (const float*)d_in[22];
  const float* bg5 = (const float*)d_in[23];
  const float* bb5 = (const float*)d_in[24];
  const float* pa5 = (const float*)d_in[25];
  const float* lw1 = (const float*)d_in[26];
  const float* lg1 = (const float*)d_in[27];
  const float* lb1 = (const float*)d_in[28];
  const float* pl1 = (const float*)d_in[29];
  const float* lw2 = (const float*)d_in[30];
  const float* lb2 = (const float*)d_in[31];
  const float* aw  = (const float*)d_in[32];
  float* out = (float*)d_out;
  float* ws = (float*)d_ws;

  float* PX = ws;                    // 1024
  float* SX = ws + 1024;             // 2
  float* S1 = ws + 1040;             // 128
  float* S2 = ws + 1168;             // 64
  float* S3 = ws + 1232;             // 128
  float* S4 = ws + 1360;             // 64
  float* S5 = ws + 1424;             // 128
  float* S6 = ws + 1552;             // 256
  float* LP = ws + 1808;             // 16
  float* P1 = ws + 2048;             // [4096][128]
  float* P2 = P1 + 524288;           // [2704][64]
  float* P3 = P2 + 173056;           // [4096][128]
  float* P4 = P3 + 524288;           // [576][64]
  float* P5 = P4 + 36864;            // [4096][128]
  float* P6 = P1;                    // [128][256] — aliases dead P1
  float* Y1 = ws + (size_t)2097152;  // [4096][169][64]  (y2 in-place, first 32/row)
  float* Y3 = Y1 + (size_t)44302336; // [4096][36][64]   (y4 in-place)
  float* Y5 = Y3 + (size_t)9437184;  // [4096][1024] k-order
  float* Z  = Y5 + (size_t)4194304;  // [4096][128]
  float* WF = Z + 524288;            // 9216 floats: conv1 weight frags
  float* WFL = WF + 16384;           // 65536 floats: lw1 frags (256 KB)

  kPrepW<<<1, 256, 0, stream>>>(cw1, (unsigned short*)WF);
  kPrepLW<<<16, 256, 0, stream>>>(lw1, (unsigned short*)WFL);
  kRedX<<<512, 256, 0, stream>>>(x, PX);
  kRedPart<<<2, 256, 0, stream>>>(PX, SX, 512, 2);
  kConv1<<<4096, 256, 0, stream>>>(x, cw0, bg0, bb0, pa0, (const unsigned short*)WF, SX, Y1, P1);
  kRedPart<<<128, 256, 0, stream>>>(P1, S1, 4096, 128);
  kConv1x1<<<2704, 256, 0, stream>>>(cw2, bg1, bb1, pa1, S1, 1.0f / 692224.0f, Y1, P2);
  kRedPart<<<64, 256, 0, stream>>>(P2, S2, 2704, 64);
  kConv3<<<4096, 64, 0, stream>>>(cw3, bg2, bb2, pa2, S2, Y1, Y3, P3);
  kRedPart<<<128, 256, 0, stream>>>(P3, S3, 4096, 128);
  kConv1x1<<<576, 256, 0, stream>>>(cw4, bg3, bb3, pa3, S3, 1.0f / 147456.0f, Y3, P4);
  kRedPart<<<64, 256, 0, stream>>>(P4, S4, 576, 64);
  kConv5<<<4096, 64, 0, stream>>>(cw5, bg4, bb4, pa4, S4, Y3, Y5, P5);
  kRedPart<<<128, 256, 0, stream>>>(P5, S5, 4096, 128);
  kFC1m<<<128, 128, 0, stream>>>((const unsigned short*)WFL, bg5, bb5, pa5, S5, Y5, Z, P6);
  kRedPart<<<256, 256, 0, stream>>>(P6, S6, 128, 256);
  kFC2Arc<<<16, 256, 0, stream>>>(Z, S6, lg1, lb1, pl1, lw2, lb2, aw, labels, out, LP);
  kFinal<<<1, 64, 0, stream>>>(LP, out);
}

// Round 6
// 400.179 us; speedup vs baseline: 3.2988x; 1.2431x over previous
//
#include <hip/hip_runtime.h>
#include <math.h>

// ---------------------------------------------------------------------------
// R6: kConv3 rewritten as bf16 MFMA implicit-GEMM (same recipe as R4 kConv1):
//   C[36pos,64och] = sum_{9taps} A[36,32ch] @ W3[32,64], 18 k-steps of 16.
//   h2 = BN2+PReLU(y2) staged bf16 [169pix][32ch] in LDS, XOR swizzle.
//   Weights pre-formatted once by kPrepW3. 4 waves: (mtile, och-half).
// Everything else identical to the passing R5 build.
// ---------------------------------------------------------------------------

typedef __attribute__((ext_vector_type(8))) short s16x8;
typedef __attribute__((ext_vector_type(16))) float f32x16;

__device__ __forceinline__ unsigned short f2bf(float f) {
  union { float f; unsigned int u; } v; v.f = f;
  unsigned int r = (v.u + 0x7FFFu + ((v.u >> 16) & 1u)) >> 16;
  return (unsigned short)r;
}

__global__ __launch_bounds__(256) void kRedX(const float* __restrict__ x,
                                             float* __restrict__ part) {
  int tid = threadIdx.x;
  int b = blockIdx.x;
  const float4* x4 = (const float4*)x;
  float s = 0.f, q = 0.f;
  for (size_t i = (size_t)b * 256 + tid; i < 802816; i += (size_t)512 * 256) {
    float4 v = x4[i];
    s += v.x + v.y + v.z + v.w;
    q += v.x * v.x + v.y * v.y + v.z * v.z + v.w * v.w;
  }
#pragma unroll
  for (int off = 32; off; off >>= 1) {
    s += __shfl_down(s, off);
    q += __shfl_down(q, off);
  }
  __shared__ float ls[4][2];
  int w = tid >> 6;
  if ((tid & 63) == 0) { ls[w][0] = s; ls[w][1] = q; }
  __syncthreads();
  if (tid == 0) {
    part[b * 2]     = ls[0][0] + ls[1][0] + ls[2][0] + ls[3][0];
    part[b * 2 + 1] = ls[0][1] + ls[1][1] + ls[2][1] + ls[3][1];
  }
}

__global__ __launch_bounds__(256) void kRedPart(const float* __restrict__ part,
                                                float* __restrict__ outp, int nb, int C2) {
  int slot = blockIdx.x;
  int tid = threadIdx.x;
  float s = 0.f;
  for (int i = tid; i < nb; i += 256) s += part[(size_t)i * C2 + slot];
#pragma unroll
  for (int off = 32; off; off >>= 1) s += __shfl_down(s, off);
  __shared__ float ls[4];
  if ((tid & 63) == 0) ls[tid >> 6] = s;
  __syncthreads();
  if (tid == 0) outp[slot] = ls[0] + ls[1] + ls[2] + ls[3];
}

// ---------------------------------------------------------------------------
// kPrepW: conv1 weights -> MFMA B-fragments (bf16).
// ---------------------------------------------------------------------------
__global__ __launch_bounds__(256) void kPrepW(const float* __restrict__ cw1,
                                              unsigned short* __restrict__ wf) {
  int tid = threadIdx.x;
  int lane = tid & 63, fb = tid >> 6;
  int m = lane & 31, kg = lane >> 5;
  for (int pass = 0; pass < 9; pass++) {
    int f = pass * 4 + fb;
    int tap = f >> 2, rem = f & 3, kt = rem >> 1, nt = rem & 1;
    int o = nt * 32 + m;
    int kb = kt * 16 + kg * 8;
    union { s16x8 v; unsigned short e[8]; } u;
#pragma unroll
    for (int j = 0; j < 8; j++)
      u.e[j] = f2bf(cw1[(size_t)o * 288 + (size_t)(kb + j) * 9 + tap]);
    ((s16x8*)wf)[f * 64 + lane] = u.v;
  }
}

// ---------------------------------------------------------------------------
// kPrepW3: conv3 weights [64o][32c][3][3] -> B-frags, k-order = tap*32 + c.
// frag f = s*2 + nt (s=0..17 k-step, nt=och half); lane l holds
// B[k = s*16 + (l>>5)*8 + j][o = nt*32 + (l&31)]; c = (s&1)*16+(l>>5)*8+j,
// tap = s>>1.
// ---------------------------------------------------------------------------
__global__ __launch_bounds__(256) void kPrepW3(const float* __restrict__ cw3,
                                               unsigned short* __restrict__ wf3) {
  int tid = threadIdx.x;
  int lane = tid & 63, fq = tid >> 6;
  int m = lane & 31, kg = lane >> 5;
  for (int pass = 0; pass < 9; pass++) {
    int f = pass * 4 + fq;  // 0..35
    int s = f >> 1, nt = f & 1;
    int tap = s >> 1;
    int o = nt * 32 + m;
    int c0 = (s & 1) * 16 + kg * 8;
    union { s16x8 v; unsigned short e[8]; } u;
#pragma unroll
    for (int j = 0; j < 8; j++)
      u.e[j] = f2bf(cw3[(size_t)o * 288 + (size_t)(c0 + j) * 9 + tap]);
    ((s16x8*)wf3)[f * 64 + lane] = u.v;
  }
}

// ---------------------------------------------------------------------------
// kConv1 (MFMA, verified R4): one image per 256-thr block (4 waves).
// ---------------------------------------------------------------------------
__global__ __launch_bounds__(256, 2) void kConv1(
    const float* __restrict__ x, const float* __restrict__ cw0,
    const float* __restrict__ bg0, const float* __restrict__ bb0,
    const float* __restrict__ pa0, const unsigned short* __restrict__ wf,
    const float* __restrict__ sx, float* __restrict__ y1, float* __restrict__ part) {
  __shared__ __align__(16) unsigned short h0t[25088];
  __shared__ __align__(16) float xs[784];
  __shared__ float s0[32], t0[32];
  __shared__ float sS[4][32], sQ[4][32];
  int tid = threadIdx.x;
  int n = blockIdx.x;
  int l = tid & 63, w = tid >> 6;
  int nt = w & 1, mh = w >> 1;
  int m = l & 31, kg = l >> 5;

  s16x8 bfr[9][2];
  const s16x8* wfp = (const s16x8*)wf;
#pragma unroll
  for (int tap = 0; tap < 9; tap++)
#pragma unroll
    for (int kt = 0; kt < 2; kt++)
      bfr[tap][kt] = wfp[(tap * 4 + kt * 2 + nt) * 64 + l];

  if (tid < 196) ((float4*)xs)[tid] = ((const float4*)(x + (size_t)n * 784))[tid];
  if (tid < 32) {
    const float invM = 1.0f / (4096.0f * 784.0f);
    float mux = sx[0] * invM;
    float varx = fmaxf(sx[1] * invM - mux * mux, 0.0f);
    float w0 = cw0[tid];
    float inv = rsqrtf(w0 * w0 * varx + 1e-5f);
    float sc = w0 * bg0[tid] * inv;
    s0[tid] = sc;
    t0[tid] = bb0[tid] - mux * sc;
  }
  __syncthreads();

  float a0p = *pa0;
  int g = tid & 3;
  float sg[8], tg[8];
#pragma unroll
  for (int j = 0; j < 8; j++) { sg[j] = s0[g * 8 + j]; tg[j] = t0[g * 8 + j]; }
  char* h0b = (char*)h0t;
  int koffW = g * 16;
  for (int t = 0; t < 13; t++) {
    int p = (tid >> 2) + t * 64;
    if (p < 784) {
      float xv = xs[p];
      union { s16x8 v; unsigned short e[8]; } u;
#pragma unroll
      for (int j = 0; j < 8; j++) {
        float v = fmaf(xv, sg[j], tg[j]);
        v = v > 0.f ? v : a0p * v;
        u.e[j] = f2bf(v);
      }
      int ad = ((p << 6) + koffW) ^ (((p >> 1) & 7) << 4);
      *(s16x8*)(h0b + ad) = u.v;
    }
  }
  __syncthreads();

  int pixb[3];
#pragma unroll
  for (int mt = 0; mt < 3; mt++) {
    int p = (mh * 3 + mt) * 32 + m;
    p = p > 168 ? 168 : p;
    pixb[mt] = (p / 13) * 56 + (p % 13) * 2;
  }
  int koffA = kg * 16;

#define Z16 {0.f,0.f,0.f,0.f, 0.f,0.f,0.f,0.f, 0.f,0.f,0.f,0.f, 0.f,0.f,0.f,0.f}
  f32x16 acc0 = Z16, acc1 = Z16, acc2 = Z16;

#define MT_STEP(ACC, MTL) { int pb = pixb[MTL]; \
  _Pragma("unroll") for (int tap = 0; tap < 9; tap++) { \
    int pix = pb + (tap / 3) * 28 + (tap % 3); \
    int ad = ((pix << 6) + koffA) ^ (((pix >> 1) & 7) << 4); \
    s16x8 a0 = *(const s16x8*)(h0b + ad); \
    s16x8 a1 = *(const s16x8*)(h0b + (ad ^ 32)); \
    ACC = __builtin_amdgcn_mfma_f32_32x32x16_bf16(a0, bfr[tap][0], ACC, 0, 0, 0); \
    ACC = __builtin_amdgcn_mfma_f32_32x32x16_bf16(a1, bfr[tap][1], ACC, 0, 0, 0); \
  } }

  MT_STEP(acc0, 0)
  MT_STEP(acc1, 1)
  MT_STEP(acc2, 2)
#undef MT_STEP

  float s = 0.f, q = 0.f;
  int och = nt * 32 + m;
#define ST_MT(ACC, MTL) { int pbase = (mh * 3 + MTL) * 32 + (kg << 2); \
  _Pragma("unroll") for (int r = 0; r < 16; r++) { \
    int p = pbase + (r & 3) + ((r >> 2) << 3); \
    if (p < 169) { float v = ACC[r]; \
      y1[((size_t)n * 169 + p) * 64 + och] = v; s += v; q += v * v; } } }

  ST_MT(acc0, 0)
  ST_MT(acc1, 1)
  ST_MT(acc2, 2)
#undef ST_MT

  s += __shfl_xor(s, 32);
  q += __shfl_xor(q, 32);
  if (l < 32) { sS[w][l] = s; sQ[w][l] = q; }
  __syncthreads();
  if (tid < 64) {
    int o = tid, wv = o >> 5;
    part[(size_t)n * 128 + o] = sS[wv][o & 31] + sS[wv + 2][o & 31];
  } else if (tid < 128) {
    int o = tid - 64, wv = o >> 5;
    part[(size_t)n * 128 + 64 + o] = sQ[wv][o & 31] + sQ[wv + 2][o & 31];
  }
}

// ---------------------------------------------------------------------------
__global__ __launch_bounds__(256) void kConv1x1(
    const float* __restrict__ wgt, const float* __restrict__ g,
    const float* __restrict__ b, const float* __restrict__ pa,
    const float* __restrict__ stats, float invM,
    float* __restrict__ buf, float* __restrict__ part) {
  __shared__ float wT[64][36];
  __shared__ float scs[64], shs[64];
  __shared__ float reds[4][32], redq[4][32];
  int tid = threadIdx.x;
  for (int e = tid; e < 2048; e += 256) {
    int o = e >> 6, c = e & 63;
    wT[c][o] = wgt[o * 64 + c];
  }
  if (tid < 64) {
    float mu = stats[tid] * invM;
    float va = fmaxf(stats[64 + tid] * invM - mu * mu, 0.0f);
    float iv = rsqrtf(va + 1e-5f);
    float sc = g[tid] * iv;
    scs[tid] = sc;
    shs[tid] = b[tid] - mu * sc;
  }
  __syncthreads();
  float al = *pa;
  size_t r = (size_t)blockIdx.x * 256 + tid;
  float* row = buf + r * 64;
  float acc[32];
#pragma unroll
  for (int o = 0; o < 32; o++) acc[o] = 0.f;
#pragma unroll
  for (int cb = 0; cb < 16; cb++) {
    float4 v4 = ((const float4*)row)[cb];
    float hv[4] = {v4.x, v4.y, v4.z, v4.w};
#pragma unroll
    for (int u = 0; u < 4; u++) {
      int c = cb * 4 + u;
      float h = fmaf(hv[u], scs[c], shs[c]);
      h = h > 0.f ? h : al * h;
      const float4* wrow = (const float4*)&wT[c][0];
#pragma unroll
      for (int ob = 0; ob < 8; ob++) {
        float4 wv = wrow[ob];
        acc[ob * 4 + 0] = fmaf(h, wv.x, acc[ob * 4 + 0]);
        acc[ob * 4 + 1] = fmaf(h, wv.y, acc[ob * 4 + 1]);
        acc[ob * 4 + 2] = fmaf(h, wv.z, acc[ob * 4 + 2]);
        acc[ob * 4 + 3] = fmaf(h, wv.w, acc[ob * 4 + 3]);
      }
    }
  }
#pragma unroll
  for (int ob = 0; ob < 8; ob++) {
    float4 st = {acc[ob * 4], acc[ob * 4 + 1], acc[ob * 4 + 2], acc[ob * 4 + 3]};
    ((float4*)row)[ob] = st;
  }
  int wv64 = tid >> 6, lane = tid & 63;
#pragma unroll
  for (int o = 0; o < 32; o++) {
    float s = acc[o], q = acc[o] * acc[o];
#pragma unroll
    for (int off = 32; off; off >>= 1) {
      s += __shfl_down(s, off);
      q += __shfl_down(q, off);
    }
    if (lane == 0) { reds[wv64][o] = s; redq[wv64][o] = q; }
  }
  __syncthreads();
  if (tid < 32) {
    part[(size_t)blockIdx.x * 64 + tid] = reds[0][tid] + reds[1][tid] + reds[2][tid] + reds[3][tid];
  } else if (tid < 64) {
    int o = tid - 32;
    part[(size_t)blockIdx.x * 64 + 32 + o] = redq[0][o] + redq[1][o] + redq[2][o] + redq[3][o];
  }
}

// ---------------------------------------------------------------------------
// kConv3m (MFMA): one image per 256-thr block (4 waves). wave w: nt=w&1 (och
// half), mt=w>>1 (pos tile: p = mt*32 + row). 18 k-steps (tap*32+c order).
// h2 staged bf16 [169pix][32ch] XOR-swizzled. y3 raw fp32 + stat partials.
// ---------------------------------------------------------------------------
__global__ __launch_bounds__(256, 3) void kConv3m(
    const unsigned short* __restrict__ wf3, const float* __restrict__ g,
    const float* __restrict__ b, const float* __restrict__ pa,
    const float* __restrict__ stats, const float* __restrict__ in,
    float* __restrict__ outb, float* __restrict__ part) {
  __shared__ __align__(16) unsigned short h2t[169 * 32];  // 10,816 B
  __shared__ float scs[32], shs[32];
  __shared__ float sS[4][32], sQ[4][32];
  int tid = threadIdx.x;
  int n = blockIdx.x;
  int l = tid & 63, w = tid >> 6;
  int nt = w & 1, mt = w >> 1;
  int m = l & 31, kg = l >> 5;

  // B fragments for this wave's och half: 18 x 16B
  s16x8 bfr[18];
  const s16x8* wfp = (const s16x8*)wf3;
#pragma unroll
  for (int s = 0; s < 18; s++) bfr[s] = wfp[(s * 2 + nt) * 64 + l];

  if (tid < 32) {
    const float invM = 1.0f / 692224.0f;
    float mu = stats[tid] * invM;
    float va = fmaxf(stats[32 + tid] * invM - mu * mu, 0.0f);
    float iv = rsqrtf(va + 1e-5f);
    float sc = g[tid] * iv;
    scs[tid] = sc;
    shs[tid] = b[tid] - mu * sc;
  }
  __syncthreads();
  float al = *pa;
  char* hb = (char*)h2t;
  {
    int pr = tid >> 2, gq = tid & 3;
    float sg[8], tg[8];
#pragma unroll
    for (int j = 0; j < 8; j++) { sg[j] = scs[gq * 8 + j]; tg[j] = shs[gq * 8 + j]; }
#pragma unroll
    for (int pass = 0; pass < 3; pass++) {
      int pp = pr + pass * 64;
      if (pp < 169) {
        const float4* src = (const float4*)(in + (size_t)n * 169 * 64 + (size_t)pp * 64 + gq * 8);
        float4 v0 = src[0], v1 = src[1];
        float t[8] = {v0.x, v0.y, v0.z, v0.w, v1.x, v1.y, v1.z, v1.w};
        union { s16x8 v; unsigned short e[8]; } u;
#pragma unroll
        for (int j = 0; j < 8; j++) {
          float h = fmaf(t[j], sg[j], tg[j]);
          h = h > 0.f ? h : al * h;
          u.e[j] = f2bf(h);
        }
        int ad = ((pp << 6) + gq * 16) ^ (((pp >> 1) & 7) << 4);
        *(s16x8*)(hb + ad) = u.v;
      }
    }
  }
  __syncthreads();

  // A row: output position p = mt*32 + m (clamped); input 13x13
  int p = mt * 32 + m;
  p = p > 35 ? 35 : p;
  int pixb = (p / 6) * 26 + (p % 6) * 2;  // (2i)*13 + 2j

#define Z16 {0.f,0.f,0.f,0.f, 0.f,0.f,0.f,0.f, 0.f,0.f,0.f,0.f, 0.f,0.f,0.f,0.f}
  f32x16 acc = Z16;
#undef Z16
#pragma unroll
  for (int s = 0; s < 18; s++) {
    int tap = s >> 1;
    int pix = pixb + (tap / 3) * 13 + (tap % 3);
    int ad = ((pix << 6) + (s & 1) * 32 + kg * 16) ^ (((pix >> 1) & 7) << 4);
    s16x8 a = *(const s16x8*)(hb + ad);
    acc = __builtin_amdgcn_mfma_f32_32x32x16_bf16(a, bfr[s], acc, 0, 0, 0);
  }

  float ss = 0.f, qq = 0.f;
  int och = nt * 32 + m;
#pragma unroll
  for (int r = 0; r < 16; r++) {
    int row = (r & 3) + ((r >> 2) << 3) + (kg << 2);
    int pp = mt * 32 + row;
    if (pp < 36) {
      float v = acc[r];
      outb[((size_t)n * 36 + pp) * 64 + och] = v;
      ss += v; qq += v * v;
    }
  }
  ss += __shfl_xor(ss, 32);
  qq += __shfl_xor(qq, 32);
  if (l < 32) { sS[w][l] = ss; sQ[w][l] = qq; }
  __syncthreads();
  if (tid < 64) {
    int o = tid, wv = o >> 5;
    part[(size_t)n * 128 + o] = sS[wv][o & 31] + sS[wv + 2][o & 31];
  } else if (tid < 128) {
    int o = tid - 64, wv = o >> 5;
    part[(size_t)n * 128 + 64 + o] = sQ[wv][o & 31] + sQ[wv + 2][o & 31];
  }
}

// ---------------------------------------------------------------------------
// kConv5: 3x3 s1, 32ch 6x6 -> 64ch 4x4. y5 stored k-order [n][o*16+p].
// ---------------------------------------------------------------------------
__global__ __launch_bounds__(64) void kConv5(
    const float* __restrict__ wgt, const float* __restrict__ g,
    const float* __restrict__ b, const float* __restrict__ pa,
    const float* __restrict__ stats, const float* __restrict__ in,
    float* __restrict__ outb, float* __restrict__ part) {
  __shared__ float h4[32][6][8];
  __shared__ float scs[32], shs[32];
  int tid = threadIdx.x;
  int n = blockIdx.x;
  if (tid < 32) {
    const float invM = 1.0f / 147456.0f;
    float mu = stats[tid] * invM;
    float va = fmaxf(stats[32 + tid] * invM - mu * mu, 0.0f);
    float iv = rsqrtf(va + 1e-5f);
    float sc = g[tid] * iv;
    scs[tid] = sc;
    shs[tid] = b[tid] - mu * sc;
  }
  __syncthreads();
  float al = *pa;
  for (int e = tid; e < 36 * 32; e += 64) {
    int p = e >> 5, c = e & 31;
    float v = in[((size_t)n * 36 + p) * 64 + c];
    v = fmaf(v, scs[c], shs[c]);
    v = v > 0.f ? v : al * v;
    h4[c][p / 6][p % 6] = v;
  }
  __syncthreads();
  int o = tid;
  float acc[16];
#pragma unroll
  for (int p = 0; p < 16; p++) acc[p] = 0.f;
  const float* wb = wgt + (size_t)o * 288;
  for (int c = 0; c < 32; c++) {
    float wr[9];
#pragma unroll
    for (int k = 0; k < 9; k++) wr[k] = wb[c * 9 + k];
#pragma unroll
    for (int ih = 0; ih < 6; ih++) {
      float4 rq[2];
      rq[0] = ((const float4*)&h4[c][ih][0])[0];
      rq[1] = ((const float4*)&h4[c][ih][0])[1];
#pragma unroll
      for (int kh = 0; kh < 3; kh++) {
        int i = ih - kh;
        if (i >= 0 && i < 4) {
#pragma unroll
          for (int kw = 0; kw < 3; kw++) {
            float wv = wr[kh * 3 + kw];
#pragma unroll
            for (int j = 0; j < 4; j++)
              acc[i * 4 + j] = fmaf(((const float*)rq)[j + kw], wv, acc[i * 4 + j]);
          }
        }
      }
    }
  }
  float s = 0.f, q = 0.f;
  float* dst = outb + (size_t)n * 1024 + o * 16;
#pragma unroll
  for (int pb = 0; pb < 4; pb++) {
    float4 st = {acc[pb * 4], acc[pb * 4 + 1], acc[pb * 4 + 2], acc[pb * 4 + 3]};
    ((float4*)dst)[pb] = st;
#pragma unroll
    for (int u = 0; u < 4; u++) { float v = acc[pb * 4 + u]; s += v; q += v * v; }
  }
  part[(size_t)n * 128 + o] = s;
  part[(size_t)n * 128 + 64 + o] = q;
}

// ---------------------------------------------------------------------------
// kPrepLW: lw1 [128f][1024k] fp32 -> bf16 B-fragments.
// ---------------------------------------------------------------------------
__global__ __launch_bounds__(256) void kPrepLW(const float* __restrict__ lw1,
                                               unsigned short* __restrict__ wfl) {
  int tid = threadIdx.x;
  int lane = tid & 63, fq = tid >> 6;
  int m = lane & 31, kg = lane >> 5;
  for (int pp = 0; pp < 4; pp++) {
    int f_idx = (blockIdx.x * 4 + pp) * 4 + fq;  // 0..255
    int ks = f_idx >> 2, nt = f_idx & 3;
    int f = nt * 32 + m;
    int kb = ks * 16 + kg * 8;
    const float4* src = (const float4*)(lw1 + (size_t)f * 1024 + kb);
    float4 v0 = src[0], v1 = src[1];
    float t[8] = {v0.x, v0.y, v0.z, v0.w, v1.x, v1.y, v1.z, v1.w};
    union { s16x8 v; unsigned short e[8]; } u;
#pragma unroll
    for (int j = 0; j < 8; j++) u.e[j] = f2bf(t[j]);
    ((s16x8*)wfl)[f_idx * 64 + lane] = u.v;
  }
}

// ---------------------------------------------------------------------------
// kFC1m: MFMA GEMM z[4096,128] = BN5PReLU(y5)[4096,1024] @ lw1^T.
// ---------------------------------------------------------------------------
__global__ __launch_bounds__(128) void kFC1m(
    const unsigned short* __restrict__ wfl, const float* __restrict__ g,
    const float* __restrict__ b, const float* __restrict__ pa,
    const float* __restrict__ stats, const float* __restrict__ y5,
    float* __restrict__ z, float* __restrict__ part) {
  __shared__ __align__(16) unsigned short hs[32 * 1024];  // 64 KB
  __shared__ float scs[64], shs[64];
  int tid = threadIdx.x;
  int n0 = blockIdx.x * 32;
  if (tid < 64) {
    const float invM = 1.0f / 65536.0f;
    float mu = stats[tid] * invM;
    float va = fmaxf(stats[64 + tid] * invM - mu * mu, 0.0f);
    float iv = rsqrtf(va + 1e-5f);
    float sc = g[tid] * iv;
    scs[tid] = sc;
    shs[tid] = b[tid] - mu * sc;
  }
  __syncthreads();
  float al = *pa;
  char* hb = (char*)hs;
  for (int i = 0; i < 32; i++) {
    int sgi = tid + i * 128;
    int nn = sgi >> 7, k8 = sgi & 127;
    int c = k8 >> 1;
    float sc = scs[c], sh = shs[c];
    const float4* src = (const float4*)(y5 + (size_t)(n0 + nn) * 1024 + k8 * 8);
    float4 v0 = src[0], v1 = src[1];
    float t[8] = {v0.x, v0.y, v0.z, v0.w, v1.x, v1.y, v1.z, v1.w};
    union { s16x8 v; unsigned short e[8]; } u;
#pragma unroll
    for (int j = 0; j < 8; j++) {
      float h = fmaf(t[j], sc, sh);
      h = h > 0.f ? h : al * h;
      u.e[j] = f2bf(h);
    }
    int ad = (nn * 2048 + k8 * 16) ^ ((nn & 7) << 4);
    *(s16x8*)(hb + ad) = u.v;
  }
  __syncthreads();

  int l = tid & 63, w = tid >> 6;
  int m = l & 31, kg = l >> 5;
#define Z16 {0.f,0.f,0.f,0.f, 0.f,0.f,0.f,0.f, 0.f,0.f,0.f,0.f, 0.f,0.f,0.f,0.f}
  f32x16 acc0 = Z16, acc1 = Z16;
#undef Z16
  const s16x8* bp = (const s16x8*)wfl;
  int abase = (m * 2048 + kg * 16) ^ ((m & 7) << 4);
#pragma unroll 4
  for (int ks = 0; ks < 64; ks++) {
    s16x8 a = *(const s16x8*)(hb + (abase ^ (ks * 32)));
    s16x8 b0 = bp[(ks * 4 + 2 * w + 0) * 64 + l];
    s16x8 b1 = bp[(ks * 4 + 2 * w + 1) * 64 + l];
    acc0 = __builtin_amdgcn_mfma_f32_32x32x16_bf16(a, b0, acc0, 0, 0, 0);
    acc1 = __builtin_amdgcn_mfma_f32_32x32x16_bf16(a, b1, acc1, 0, 0, 0);
  }

  float s0 = 0.f, q0 = 0.f, s1 = 0.f, q1 = 0.f;
  int f0c = (2 * w) * 32 + m, f1c = (2 * w + 1) * 32 + m;
#pragma unroll
  for (int r = 0; r < 16; r++) {
    int n = (r & 3) + ((r >> 2) << 3) + (kg << 2);
    float v0 = acc0[r], v1 = acc1[r];
    z[(size_t)(n0 + n) * 128 + f0c] = v0;
    z[(size_t)(n0 + n) * 128 + f1c] = v1;
    s0 += v0; q0 += v0 * v0; s1 += v1; q1 += v1 * v1;
  }
  s0 += __shfl_xor(s0, 32); q0 += __shfl_xor(q0, 32);
  s1 += __shfl_xor(s1, 32); q1 += __shfl_xor(q1, 32);
  if (l < 32) {
    size_t base = (size_t)blockIdx.x * 256;
    part[base + w * 64 + m] = s0;
    part[base + w * 64 + 32 + m] = s1;
    part[base + 128 + w * 64 + m] = q0;
    part[base + 128 + w * 64 + 32 + m] = q1;
  }
}

// ---------------------------------------------------------------------------
__global__ __launch_bounds__(256) void kFC2Arc(
    const float* __restrict__ z, const float* __restrict__ s6,
    const float* __restrict__ lg1, const float* __restrict__ lb1,
    const float* __restrict__ pl1, const float* __restrict__ lw2,
    const float* __restrict__ lb2, const float* __restrict__ aw,
    const int* __restrict__ labels, float* __restrict__ out,
    float* __restrict__ lpart) {
  __shared__ float scz[128], shz[128], w2a[128], w2b[128];
  __shared__ float awl[20];
  __shared__ float lred[4];
  int tid = threadIdx.x;
  if (tid < 128) {
    const float invM = 1.0f / 4096.0f;
    float mu = s6[tid] * invM;
    float va = fmaxf(s6[128 + tid] * invM - mu * mu, 0.0f);
    float iv = rsqrtf(va + 1e-5f);
    float sc = lg1[tid] * iv;
    scz[tid] = sc;
    shz[tid] = lb1[tid] - mu * sc;
    w2a[tid] = lw2[tid];
    w2b[tid] = lw2[128 + tid];
  }
  if (tid < 20) awl[tid] = aw[tid];
  __syncthreads();
  float al = *pl1;
  int n = blockIdx.x * 256 + tid;
  const float4* zr = (const float4*)(z + (size_t)n * 128);
  float f0 = lb2[0], f1 = lb2[1];
#pragma unroll
  for (int kb = 0; kb < 32; kb++) {
    float4 v = zr[kb];
    float hv[4] = {v.x, v.y, v.z, v.w};
#pragma unroll
    for (int u = 0; u < 4; u++) {
      int k = kb * 4 + u;
      float h = fmaf(hv[u], scz[k], shz[k]);
      h = h > 0.f ? h : al * h;
      f0 = fmaf(h, w2a[k], f0);
      f1 = fmaf(h, w2b[k], f1);
    }
  }
  out[(size_t)n * 2] = f0;
  out[(size_t)n * 2 + 1] = f1;
  float nrm = sqrtf(fmaxf(f0 * f0 + f1 * f1, 1e-30f));
  float xn0 = f0 / nrm, xn1 = f1 / nrm;
  int lab = labels[n];
  float wv[10];
  float m64 = -3.4e38f;
#pragma unroll
  for (int j = 0; j < 10; j++) {
    float w = xn0 * awl[2 * j] + xn1 * awl[2 * j + 1];
    wv[j] = w;
    out[8192 + (size_t)n * 10 + j] = w;
    m64 = fmaxf(m64, 64.0f * w);
  }
  float tgt = wv[0];
#pragma unroll
  for (int j = 1; j < 10; j++) if (j == lab) tgt = wv[j];
  if (lab == 0) tgt = wv[0];
  const float CLO = (float)(-1.0 + 1e-7);
  const float CHI = (float)(1.0 - 1e-7);
  float t = fminf(fmaxf(tgt, CLO), CHI);
  float num = 64.0f * (t * 0.87758256189037276f - 0.47942553860420301f * sqrtf(fmaxf(1.0f - t * t, 0.0f)));
  float L = fmaxf(num, m64);
  float dsum = expf(num - L) - expf(64.0f * tgt - L);
#pragma unroll
  for (int j = 0; j < 10; j++) dsum += expf(64.0f * wv[j] - L);
  dsum = fmaxf(dsum, 1e-30f);
  float li = num - (L + logf(dsum));
#pragma unroll
  for (int off = 32; off; off >>= 1) li += __shfl_down(li, off);
  if ((tid & 63) == 0) lred[tid >> 6] = li;
  __syncthreads();
  if (tid == 0) lpart[blockIdx.x] = lred[0] + lred[1] + lred[2] + lred[3];
}

__global__ void kFinal(const float* __restrict__ lpart, float* __restrict__ out) {
  int tid = threadIdx.x;
  float v = (tid < 16) ? lpart[tid] : 0.f;
#pragma unroll
  for (int off = 8; off; off >>= 1) v += __shfl_down(v, off);
  if (tid == 0) out[49152] = -v * (1.0f / 4096.0f);
}

// ---------------------------------------------------------------------------
extern "C" void kernel_launch(void* const* d_in, const int* in_sizes, int n_in,
                              void* d_out, int out_size, void* d_ws, size_t ws_size,
                              hipStream_t stream) {
  const float* x   = (const float*)d_in[0];
  const int* labels = (const int*)d_in[1];
  const float* cw0 = (const float*)d_in[2];
  const float* bg0 = (const float*)d_in[3];
  const float* bb0 = (const float*)d_in[4];
  const float* pa0 = (const float*)d_in[5];
  const float* cw1 = (const float*)d_in[6];
  const float* bg1 = (const float*)d_in[7];
  const float* bb1 = (const float*)d_in[8];
  const float* pa1 = (const float*)d_in[9];
  const float* cw2 = (const float*)d_in[10];
  const float* bg2 = (const float*)d_in[11];
  const float* bb2 = (const float*)d_in[12];
  const float* pa2 = (const float*)d_in[13];
  const float* cw3 = (const float*)d_in[14];
  const float* bg3 = (const float*)d_in[15];
  const float* bb3 = (const float*)d_in[16];
  const float* pa3 = (const float*)d_in[17];
  const float* cw4 = (const float*)d_in[18];
  const float* bg4 = (const float*)d_in[19];
  const float* bb4 = (const float*)d_in[20];
  const float* pa4 = (const float*)d_in[21];
  const float* cw5 = (const float*)d_in[22];
  const float* bg5 = (const float*)d_in[23];
  const float* bb5 = (const float*)d_in[24];
  const float* pa5 = (const float*)d_in[25];
  const float* lw1 = (const float*)d_in[26];
  const float* lg1 = (const float*)d_in[27];
  const float* lb1 = (const float*)d_in[28];
  const float* pl1 = (const float*)d_in[29];
  const float* lw2 = (const float*)d_in[30];
  const float* lb2 = (const float*)d_in[31];
  const float* aw  = (const float*)d_in[32];
  float* out = (float*)d_out;
  float* ws = (float*)d_ws;

  float* PX = ws;                    // 1024
  float* SX = ws + 1024;             // 2
  float* S1 = ws + 1040;             // 128
  float* S2 = ws + 1168;             // 64
  float* S3 = ws + 1232;             // 128
  float* S4 = ws + 1360;             // 64
  float* S5 = ws + 1424;             // 128
  float* S6 = ws + 1552;             // 256
  float* LP = ws + 1808;             // 16
  float* P1 = ws + 2048;             // [4096][128]
  float* P2 = P1 + 524288;           // [2704][64]
  float* P3 = P2 + 173056;           // [4096][128]
  float* P4 = P3 + 524288;           // [576][64]
  float* P5 = P4 + 36864;            // [4096][128]
  float* P6 = P1;                    // [128][256] — aliases dead P1
  float* Y1 = ws + (size_t)2097152;  // [4096][169][64]  (y2 in-place, first 32/row)
  float* Y3 = Y1 + (size_t)44302336; // [4096][36][64]   (y4 in-place)
  float* Y5 = Y3 + (size_t)9437184;  // [4096][1024] k-order
  float* Z  = Y5 + (size_t)4194304;  // [4096][128]
  float* WF = Z + 524288;            // conv1 weight frags (36,864B)
  float* WFL = WF + 16384;           // lw1 frags (256 KB)
  float* WF3 = WFL + 65536;          // conv3 weight frags (36,864B)

  kPrepW<<<1, 256, 0, stream>>>(cw1, (unsigned short*)WF);
  kPrepW3<<<1, 256, 0, stream>>>(cw3, (unsigned short*)WF3);
  kPrepLW<<<16, 256, 0, stream>>>(lw1, (unsigned short*)WFL);
  kRedX<<<512, 256, 0, stream>>>(x, PX);
  kRedPart<<<2, 256, 0, stream>>>(PX, SX, 512, 2);
  kConv1<<<4096, 256, 0, stream>>>(x, cw0, bg0, bb0, pa0, (const unsigned short*)WF, SX, Y1, P1);
  kRedPart<<<128, 256, 0, stream>>>(P1, S1, 4096, 128);
  kConv1x1<<<2704, 256, 0, stream>>>(cw2, bg1, bb1, pa1, S1, 1.0f / 692224.0f, Y1, P2);
  kRedPart<<<64, 256, 0, stream>>>(P2, S2, 2704, 64);
  kConv3m<<<4096, 256, 0, stream>>>((const unsigned short*)WF3, bg2, bb2, pa2, S2, Y1, Y3, P3);
  kRedPart<<<128, 256, 0, stream>>>(P3, S3, 4096, 128);
  kConv1x1<<<576, 256, 0, stream>>>(cw4, bg3, bb3, pa3, S3, 1.0f / 147456.0f, Y3, P4);
  kRedPart<<<64, 256, 0, stream>>>(P4, S4, 576, 64);
  kConv5<<<4096, 64, 0, stream>>>(cw5, bg4, bb4, pa4, S4, Y3, Y5, P5);
  kRedPart<<<128, 256, 0, stream>>>(P5, S5, 4096, 128);
  kFC1m<<<128, 128, 0, stream>>>((const unsigned short*)WFL, bg5, bb5, pa5, S5, Y5, Z, P6);
  kRedPart<<<256, 256, 0, stream>>>(P6, S6, 128, 256);
  kFC2Arc<<<16, 256, 0, stream>>>(Z, S6, lg1, lb1, pl1, lw2, lb2, aw, labels, out, LP);
  kFinal<<<1, 64, 0, stream>>>(LP, out);
}

// Round 7
// 380.012 us; speedup vs baseline: 3.4738x; 1.0531x over previous
//
#include <hip/hip_runtime.h>
#include <math.h>

// ---------------------------------------------------------------------------
// R7: bf16 + compact activation streams (stats remain fp32, computed from
// producer registers):
//   y1: bf16 [4096][169][64]  (was fp32, 177MB -> 88MB)
//   y2: bf16 compact [4096][169][32] (was in-place half rows, 88MB -> 44MB)
//   y3: bf16 [4096][36][64]; y4: bf16 compact [4096][36][32]
//   kConv1x1b: bf16-in/bf16-out streaming 1x1 conv (conv2, conv4)
// kConv1/kConv3m/kFC1m MFMA paths otherwise unchanged from R6 (verified).
// ---------------------------------------------------------------------------

typedef __attribute__((ext_vector_type(8))) short s16x8;
typedef __attribute__((ext_vector_type(16))) float f32x16;

__device__ __forceinline__ unsigned short f2bf(float f) {
  union { float f; unsigned int u; } v; v.f = f;
  unsigned int r = (v.u + 0x7FFFu + ((v.u >> 16) & 1u)) >> 16;
  return (unsigned short)r;
}
__device__ __forceinline__ float bf2f(unsigned short h) {
  union { unsigned int u; float f; } t; t.u = ((unsigned int)h) << 16; return t.f;
}

__global__ __launch_bounds__(256) void kRedX(const float* __restrict__ x,
                                             float* __restrict__ part) {
  int tid = threadIdx.x;
  int b = blockIdx.x;
  const float4* x4 = (const float4*)x;
  float s = 0.f, q = 0.f;
  for (size_t i = (size_t)b * 256 + tid; i < 802816; i += (size_t)512 * 256) {
    float4 v = x4[i];
    s += v.x + v.y + v.z + v.w;
    q += v.x * v.x + v.y * v.y + v.z * v.z + v.w * v.w;
  }
#pragma unroll
  for (int off = 32; off; off >>= 1) {
    s += __shfl_down(s, off);
    q += __shfl_down(q, off);
  }
  __shared__ float ls[4][2];
  int w = tid >> 6;
  if ((tid & 63) == 0) { ls[w][0] = s; ls[w][1] = q; }
  __syncthreads();
  if (tid == 0) {
    part[b * 2]     = ls[0][0] + ls[1][0] + ls[2][0] + ls[3][0];
    part[b * 2 + 1] = ls[0][1] + ls[1][1] + ls[2][1] + ls[3][1];
  }
}

__global__ __launch_bounds__(256) void kRedPart(const float* __restrict__ part,
                                                float* __restrict__ outp, int nb, int C2) {
  int slot = blockIdx.x;
  int tid = threadIdx.x;
  float s = 0.f;
  for (int i = tid; i < nb; i += 256) s += part[(size_t)i * C2 + slot];
#pragma unroll
  for (int off = 32; off; off >>= 1) s += __shfl_down(s, off);
  __shared__ float ls[4];
  if ((tid & 63) == 0) ls[tid >> 6] = s;
  __syncthreads();
  if (tid == 0) outp[slot] = ls[0] + ls[1] + ls[2] + ls[3];
}

// ---------------------------------------------------------------------------
__global__ __launch_bounds__(256) void kPrepW(const float* __restrict__ cw1,
                                              unsigned short* __restrict__ wf) {
  int tid = threadIdx.x;
  int lane = tid & 63, fb = tid >> 6;
  int m = lane & 31, kg = lane >> 5;
  for (int pass = 0; pass < 9; pass++) {
    int f = pass * 4 + fb;
    int tap = f >> 2, rem = f & 3, kt = rem >> 1, nt = rem & 1;
    int o = nt * 32 + m;
    int kb = kt * 16 + kg * 8;
    union { s16x8 v; unsigned short e[8]; } u;
#pragma unroll
    for (int j = 0; j < 8; j++)
      u.e[j] = f2bf(cw1[(size_t)o * 288 + (size_t)(kb + j) * 9 + tap]);
    ((s16x8*)wf)[f * 64 + lane] = u.v;
  }
}

__global__ __launch_bounds__(256) void kPrepW3(const float* __restrict__ cw3,
                                               unsigned short* __restrict__ wf3) {
  int tid = threadIdx.x;
  int lane = tid & 63, fq = tid >> 6;
  int m = lane & 31, kg = lane >> 5;
  for (int pass = 0; pass < 9; pass++) {
    int f = pass * 4 + fq;  // 0..35
    int s = f >> 1, nt = f & 1;
    int tap = s >> 1;
    int o = nt * 32 + m;
    int c0 = (s & 1) * 16 + kg * 8;
    union { s16x8 v; unsigned short e[8]; } u;
#pragma unroll
    for (int j = 0; j < 8; j++)
      u.e[j] = f2bf(cw3[(size_t)o * 288 + (size_t)(c0 + j) * 9 + tap]);
    ((s16x8*)wf3)[f * 64 + lane] = u.v;
  }
}

// ---------------------------------------------------------------------------
// kConv1 (MFMA): y1 out is now bf16.
// ---------------------------------------------------------------------------
__global__ __launch_bounds__(256, 2) void kConv1(
    const float* __restrict__ x, const float* __restrict__ cw0,
    const float* __restrict__ bg0, const float* __restrict__ bb0,
    const float* __restrict__ pa0, const unsigned short* __restrict__ wf,
    const float* __restrict__ sx, unsigned short* __restrict__ y1b,
    float* __restrict__ part) {
  __shared__ __align__(16) unsigned short h0t[25088];
  __shared__ __align__(16) float xs[784];
  __shared__ float s0[32], t0[32];
  __shared__ float sS[4][32], sQ[4][32];
  int tid = threadIdx.x;
  int n = blockIdx.x;
  int l = tid & 63, w = tid >> 6;
  int nt = w & 1, mh = w >> 1;
  int m = l & 31, kg = l >> 5;

  s16x8 bfr[9][2];
  const s16x8* wfp = (const s16x8*)wf;
#pragma unroll
  for (int tap = 0; tap < 9; tap++)
#pragma unroll
    for (int kt = 0; kt < 2; kt++)
      bfr[tap][kt] = wfp[(tap * 4 + kt * 2 + nt) * 64 + l];

  if (tid < 196) ((float4*)xs)[tid] = ((const float4*)(x + (size_t)n * 784))[tid];
  if (tid < 32) {
    const float invM = 1.0f / (4096.0f * 784.0f);
    float mux = sx[0] * invM;
    float varx = fmaxf(sx[1] * invM - mux * mux, 0.0f);
    float w0 = cw0[tid];
    float inv = rsqrtf(w0 * w0 * varx + 1e-5f);
    float sc = w0 * bg0[tid] * inv;
    s0[tid] = sc;
    t0[tid] = bb0[tid] - mux * sc;
  }
  __syncthreads();

  float a0p = *pa0;
  int g = tid & 3;
  float sg[8], tg[8];
#pragma unroll
  for (int j = 0; j < 8; j++) { sg[j] = s0[g * 8 + j]; tg[j] = t0[g * 8 + j]; }
  char* h0b = (char*)h0t;
  int koffW = g * 16;
  for (int t = 0; t < 13; t++) {
    int p = (tid >> 2) + t * 64;
    if (p < 784) {
      float xv = xs[p];
      union { s16x8 v; unsigned short e[8]; } u;
#pragma unroll
      for (int j = 0; j < 8; j++) {
        float v = fmaf(xv, sg[j], tg[j]);
        v = v > 0.f ? v : a0p * v;
        u.e[j] = f2bf(v);
      }
      int ad = ((p << 6) + koffW) ^ (((p >> 1) & 7) << 4);
      *(s16x8*)(h0b + ad) = u.v;
    }
  }
  __syncthreads();

  int pixb[3];
#pragma unroll
  for (int mt = 0; mt < 3; mt++) {
    int p = (mh * 3 + mt) * 32 + m;
    p = p > 168 ? 168 : p;
    pixb[mt] = (p / 13) * 56 + (p % 13) * 2;
  }
  int koffA = kg * 16;

#define Z16 {0.f,0.f,0.f,0.f, 0.f,0.f,0.f,0.f, 0.f,0.f,0.f,0.f, 0.f,0.f,0.f,0.f}
  f32x16 acc0 = Z16, acc1 = Z16, acc2 = Z16;

#define MT_STEP(ACC, MTL) { int pb = pixb[MTL]; \
  _Pragma("unroll") for (int tap = 0; tap < 9; tap++) { \
    int pix = pb + (tap / 3) * 28 + (tap % 3); \
    int ad = ((pix << 6) + koffA) ^ (((pix >> 1) & 7) << 4); \
    s16x8 a0 = *(const s16x8*)(h0b + ad); \
    s16x8 a1 = *(const s16x8*)(h0b + (ad ^ 32)); \
    ACC = __builtin_amdgcn_mfma_f32_32x32x16_bf16(a0, bfr[tap][0], ACC, 0, 0, 0); \
    ACC = __builtin_amdgcn_mfma_f32_32x32x16_bf16(a1, bfr[tap][1], ACC, 0, 0, 0); \
  } }

  MT_STEP(acc0, 0)
  MT_STEP(acc1, 1)
  MT_STEP(acc2, 2)
#undef MT_STEP

  float s = 0.f, q = 0.f;
  int och = nt * 32 + m;
#define ST_MT(ACC, MTL) { int pbase = (mh * 3 + MTL) * 32 + (kg << 2); \
  _Pragma("unroll") for (int r = 0; r < 16; r++) { \
    int p = pbase + (r & 3) + ((r >> 2) << 3); \
    if (p < 169) { float v = ACC[r]; \
      y1b[((size_t)n * 169 + p) * 64 + och] = f2bf(v); s += v; q += v * v; } } }

  ST_MT(acc0, 0)
  ST_MT(acc1, 1)
  ST_MT(acc2, 2)
#undef ST_MT

  s += __shfl_xor(s, 32);
  q += __shfl_xor(q, 32);
  if (l < 32) { sS[w][l] = s; sQ[w][l] = q; }
  __syncthreads();
  if (tid < 64) {
    int o = tid, wv = o >> 5;
    part[(size_t)n * 128 + o] = sS[wv][o & 31] + sS[wv + 2][o & 31];
  } else if (tid < 128) {
    int o = tid - 64, wv = o >> 5;
    part[(size_t)n * 128 + 64 + o] = sQ[wv][o & 31] + sQ[wv + 2][o & 31];
  }
}

// ---------------------------------------------------------------------------
// kConv1x1b: 64 -> 32 pointwise, bf16 rows [R][64] in, compact bf16 [R][32]
// out, BN+PReLU on load (fp32), stats partials [32 sums][32 sq] per block.
// ---------------------------------------------------------------------------
__global__ __launch_bounds__(256) void kConv1x1b(
    const float* __restrict__ wgt, const float* __restrict__ g,
    const float* __restrict__ b, const float* __restrict__ pa,
    const float* __restrict__ stats, float invM,
    const unsigned short* __restrict__ in, unsigned short* __restrict__ outb,
    float* __restrict__ part) {
  __shared__ float wT[64][36];
  __shared__ float scs[64], shs[64];
  __shared__ float reds[4][32], redq[4][32];
  int tid = threadIdx.x;
  for (int e = tid; e < 2048; e += 256) {
    int o = e >> 6, c = e & 63;
    wT[c][o] = wgt[o * 64 + c];
  }
  if (tid < 64) {
    float mu = stats[tid] * invM;
    float va = fmaxf(stats[64 + tid] * invM - mu * mu, 0.0f);
    float iv = rsqrtf(va + 1e-5f);
    float sc = g[tid] * iv;
    scs[tid] = sc;
    shs[tid] = b[tid] - mu * sc;
  }
  __syncthreads();
  float al = *pa;
  size_t r = (size_t)blockIdx.x * 256 + tid;
  const s16x8* row = (const s16x8*)(in + r * 64);
  float acc[32];
#pragma unroll
  for (int o = 0; o < 32; o++) acc[o] = 0.f;
#pragma unroll
  for (int cb = 0; cb < 8; cb++) {
    union { s16x8 v; unsigned short e[8]; } u;
    u.v = row[cb];
#pragma unroll
    for (int j = 0; j < 8; j++) {
      int c = cb * 8 + j;
      float h = fmaf(bf2f(u.e[j]), scs[c], shs[c]);
      h = h > 0.f ? h : al * h;
      const float4* wrow = (const float4*)&wT[c][0];
#pragma unroll
      for (int ob = 0; ob < 8; ob++) {
        float4 wv = wrow[ob];
        acc[ob * 4 + 0] = fmaf(h, wv.x, acc[ob * 4 + 0]);
        acc[ob * 4 + 1] = fmaf(h, wv.y, acc[ob * 4 + 1]);
        acc[ob * 4 + 2] = fmaf(h, wv.z, acc[ob * 4 + 2]);
        acc[ob * 4 + 3] = fmaf(h, wv.w, acc[ob * 4 + 3]);
      }
    }
  }
  s16x8* dst = (s16x8*)(outb + r * 32);
#pragma unroll
  for (int ob = 0; ob < 4; ob++) {
    union { s16x8 v; unsigned short e[8]; } u;
#pragma unroll
    for (int j = 0; j < 8; j++) u.e[j] = f2bf(acc[ob * 8 + j]);
    dst[ob] = u.v;
  }
  int wv64 = tid >> 6, lane = tid & 63;
#pragma unroll
  for (int o = 0; o < 32; o++) {
    float s = acc[o], q = acc[o] * acc[o];
#pragma unroll
    for (int off = 32; off; off >>= 1) {
      s += __shfl_down(s, off);
      q += __shfl_down(q, off);
    }
    if (lane == 0) { reds[wv64][o] = s; redq[wv64][o] = q; }
  }
  __syncthreads();
  if (tid < 32) {
    part[(size_t)blockIdx.x * 64 + tid] = reds[0][tid] + reds[1][tid] + reds[2][tid] + reds[3][tid];
  } else if (tid < 64) {
    int o = tid - 32;
    part[(size_t)blockIdx.x * 64 + 32 + o] = redq[0][o] + redq[1][o] + redq[2][o] + redq[3][o];
  }
}

// ---------------------------------------------------------------------------
// kConv3m (MFMA): input compact bf16 y2 [169][32]; output bf16 y3 [36][64].
// ---------------------------------------------------------------------------
__global__ __launch_bounds__(256, 3) void kConv3m(
    const unsigned short* __restrict__ wf3, const float* __restrict__ g,
    const float* __restrict__ b, const float* __restrict__ pa,
    const float* __restrict__ stats, const unsigned short* __restrict__ in,
    unsigned short* __restrict__ outb, float* __restrict__ part) {
  __shared__ __align__(16) unsigned short h2t[169 * 32];  // 10,816 B
  __shared__ float scs[32], shs[32];
  __shared__ float sS[4][32], sQ[4][32];
  int tid = threadIdx.x;
  int n = blockIdx.x;
  int l = tid & 63, w = tid >> 6;
  int nt = w & 1, mt = w >> 1;
  int m = l & 31, kg = l >> 5;

  s16x8 bfr[18];
  const s16x8* wfp = (const s16x8*)wf3;
#pragma unroll
  for (int s = 0; s < 18; s++) bfr[s] = wfp[(s * 2 + nt) * 64 + l];

  if (tid < 32) {
    const float invM = 1.0f / 692224.0f;
    float mu = stats[tid] * invM;
    float va = fmaxf(stats[32 + tid] * invM - mu * mu, 0.0f);
    float iv = rsqrtf(va + 1e-5f);
    float sc = g[tid] * iv;
    scs[tid] = sc;
    shs[tid] = b[tid] - mu * sc;
  }
  __syncthreads();
  float al = *pa;
  char* hb = (char*)h2t;
  for (int e = tid; e < 676; e += 256) {
    int p = e >> 2, q = e & 3;
    union { s16x8 v; unsigned short e8[8]; } u, o8;
    u.v = ((const s16x8*)(in + ((size_t)n * 169 + p) * 32))[q];
#pragma unroll
    for (int j = 0; j < 8; j++) {
      int c = q * 8 + j;
      float h = fmaf(bf2f(u.e8[j]), scs[c], shs[c]);
      h = h > 0.f ? h : al * h;
      o8.e8[j] = f2bf(h);
    }
    int ad = ((p << 6) + q * 16) ^ (((p >> 1) & 7) << 4);
    *(s16x8*)(hb + ad) = o8.v;
  }
  __syncthreads();

  int p = mt * 32 + m;
  p = p > 35 ? 35 : p;
  int pixb = (p / 6) * 26 + (p % 6) * 2;  // (2i)*13 + 2j

#define Z16 {0.f,0.f,0.f,0.f, 0.f,0.f,0.f,0.f, 0.f,0.f,0.f,0.f, 0.f,0.f,0.f,0.f}
  f32x16 acc = Z16;
#undef Z16
#pragma unroll
  for (int s = 0; s < 18; s++) {
    int tap = s >> 1;
    int pix = pixb + (tap / 3) * 13 + (tap % 3);
    int ad = ((pix << 6) + (s & 1) * 32 + kg * 16) ^ (((pix >> 1) & 7) << 4);
    s16x8 a = *(const s16x8*)(hb + ad);
    acc = __builtin_amdgcn_mfma_f32_32x32x16_bf16(a, bfr[s], acc, 0, 0, 0);
  }

  float ss = 0.f, qq = 0.f;
  int och = nt * 32 + m;
#pragma unroll
  for (int r = 0; r < 16; r++) {
    int row = (r & 3) + ((r >> 2) << 3) + (kg << 2);
    int pp = mt * 32 + row;
    if (pp < 36) {
      float v = acc[r];
      outb[((size_t)n * 36 + pp) * 64 + och] = f2bf(v);
      ss += v; qq += v * v;
    }
  }
  ss += __shfl_xor(ss, 32);
  qq += __shfl_xor(qq, 32);
  if (l < 32) { sS[w][l] = ss; sQ[w][l] = qq; }
  __syncthreads();
  if (tid < 64) {
    int o = tid, wv = o >> 5;
    part[(size_t)n * 128 + o] = sS[wv][o & 31] + sS[wv + 2][o & 31];
  } else if (tid < 128) {
    int o = tid - 64, wv = o >> 5;
    part[(size_t)n * 128 + 64 + o] = sQ[wv][o & 31] + sQ[wv + 2][o & 31];
  }
}

// ---------------------------------------------------------------------------
// kConv5: input compact bf16 y4 [36][32]; output y5 fp32 k-order [n][o*16+p].
// ---------------------------------------------------------------------------
__global__ __launch_bounds__(64) void kConv5(
    const float* __restrict__ wgt, const float* __restrict__ g,
    const float* __restrict__ b, const float* __restrict__ pa,
    const float* __restrict__ stats, const unsigned short* __restrict__ in,
    float* __restrict__ outb, float* __restrict__ part) {
  __shared__ float h4[32][6][8];
  __shared__ float scs[32], shs[32];
  int tid = threadIdx.x;
  int n = blockIdx.x;
  if (tid < 32) {
    const float invM = 1.0f / 147456.0f;
    float mu = stats[tid] * invM;
    float va = fmaxf(stats[32 + tid] * invM - mu * mu, 0.0f);
    float iv = rsqrtf(va + 1e-5f);
    float sc = g[tid] * iv;
    scs[tid] = sc;
    shs[tid] = b[tid] - mu * sc;
  }
  __syncthreads();
  float al = *pa;
  for (int e = tid; e < 144; e += 64) {
    int p = e >> 2, q = e & 3;
    union { s16x8 v; unsigned short e8[8]; } u;
    u.v = ((const s16x8*)(in + ((size_t)n * 36 + p) * 32))[q];
#pragma unroll
    for (int j = 0; j < 8; j++) {
      int c = q * 8 + j;
      float v = fmaf(bf2f(u.e8[j]), scs[c], shs[c]);
      v = v > 0.f ? v : al * v;
      h4[c][p / 6][p % 6] = v;
    }
  }
  __syncthreads();
  int o = tid;
  float acc[16];
#pragma unroll
  for (int p = 0; p < 16; p++) acc[p] = 0.f;
  const float* wb = wgt + (size_t)o * 288;
  for (int c = 0; c < 32; c++) {
    float wr[9];
#pragma unroll
    for (int k = 0; k < 9; k++) wr[k] = wb[c * 9 + k];
#pragma unroll
    for (int ih = 0; ih < 6; ih++) {
      float4 rq[2];
      rq[0] = ((const float4*)&h4[c][ih][0])[0];
      rq[1] = ((const float4*)&h4[c][ih][0])[1];
#pragma unroll
      for (int kh = 0; kh < 3; kh++) {
        int i = ih - kh;
        if (i >= 0 && i < 4) {
#pragma unroll
          for (int kw = 0; kw < 3; kw++) {
            float wv = wr[kh * 3 + kw];
#pragma unroll
            for (int j = 0; j < 4; j++)
              acc[i * 4 + j] = fmaf(((const float*)rq)[j + kw], wv, acc[i * 4 + j]);
          }
        }
      }
    }
  }
  float s = 0.f, q = 0.f;
  float* dst = outb + (size_t)n * 1024 + o * 16;
#pragma unroll
  for (int pb = 0; pb < 4; pb++) {
    float4 st = {acc[pb * 4], acc[pb * 4 + 1], acc[pb * 4 + 2], acc[pb * 4 + 3]};
    ((float4*)dst)[pb] = st;
#pragma unroll
    for (int u = 0; u < 4; u++) { float v = acc[pb * 4 + u]; s += v; q += v * v; }
  }
  part[(size_t)n * 128 + o] = s;
  part[(size_t)n * 128 + 64 + o] = q;
}

// ---------------------------------------------------------------------------
__global__ __launch_bounds__(256) void kPrepLW(const float* __restrict__ lw1,
                                               unsigned short* __restrict__ wfl) {
  int tid = threadIdx.x;
  int lane = tid & 63, fq = tid >> 6;
  int m = lane & 31, kg = lane >> 5;
  for (int pp = 0; pp < 4; pp++) {
    int f_idx = (blockIdx.x * 4 + pp) * 4 + fq;  // 0..255
    int ks = f_idx >> 2, nt = f_idx & 3;
    int f = nt * 32 + m;
    int kb = ks * 16 + kg * 8;
    const float4* src = (const float4*)(lw1 + (size_t)f * 1024 + kb);
    float4 v0 = src[0], v1 = src[1];
    float t[8] = {v0.x, v0.y, v0.z, v0.w, v1.x, v1.y, v1.z, v1.w};
    union { s16x8 v; unsigned short e[8]; } u;
#pragma unroll
    for (int j = 0; j < 8; j++) u.e[j] = f2bf(t[j]);
    ((s16x8*)wfl)[f_idx * 64 + lane] = u.v;
  }
}

// ---------------------------------------------------------------------------
__global__ __launch_bounds__(128) void kFC1m(
    const unsigned short* __restrict__ wfl, const float* __restrict__ g,
    const float* __restrict__ b, const float* __restrict__ pa,
    const float* __restrict__ stats, const float* __restrict__ y5,
    float* __restrict__ z, float* __restrict__ part) {
  __shared__ __align__(16) unsigned short hs[32 * 1024];  // 64 KB
  __shared__ float scs[64], shs[64];
  int tid = threadIdx.x;
  int n0 = blockIdx.x * 32;
  if (tid < 64) {
    const float invM = 1.0f / 65536.0f;
    float mu = stats[tid] * invM;
    float va = fmaxf(stats[64 + tid] * invM - mu * mu, 0.0f);
    float iv = rsqrtf(va + 1e-5f);
    float sc = g[tid] * iv;
    scs[tid] = sc;
    shs[tid] = b[tid] - mu * sc;
  }
  __syncthreads();
  float al = *pa;
  char* hb = (char*)hs;
  for (int i = 0; i < 32; i++) {
    int sgi = tid + i * 128;
    int nn = sgi >> 7, k8 = sgi & 127;
    int c = k8 >> 1;
    float sc = scs[c], sh = shs[c];
    const float4* src = (const float4*)(y5 + (size_t)(n0 + nn) * 1024 + k8 * 8);
    float4 v0 = src[0], v1 = src[1];
    float t[8] = {v0.x, v0.y, v0.z, v0.w, v1.x, v1.y, v1.z, v1.w};
    union { s16x8 v; unsigned short e[8]; } u;
#pragma unroll
    for (int j = 0; j < 8; j++) {
      float h = fmaf(t[j], sc, sh);
      h = h > 0.f ? h : al * h;
      u.e[j] = f2bf(h);
    }
    int ad = (nn * 2048 + k8 * 16) ^ ((nn & 7) << 4);
    *(s16x8*)(hb + ad) = u.v;
  }
  __syncthreads();

  int l = tid & 63, w = tid >> 6;
  int m = l & 31, kg = l >> 5;
#define Z16 {0.f,0.f,0.f,0.f, 0.f,0.f,0.f,0.f, 0.f,0.f,0.f,0.f, 0.f,0.f,0.f,0.f}
  f32x16 acc0 = Z16, acc1 = Z16;
#undef Z16
  const s16x8* bp = (const s16x8*)wfl;
  int abase = (m * 2048 + kg * 16) ^ ((m & 7) << 4);
#pragma unroll 4
  for (int ks = 0; ks < 64; ks++) {
    s16x8 a = *(const s16x8*)(hb + (abase ^ (ks * 32)));
    s16x8 b0 = bp[(ks * 4 + 2 * w + 0) * 64 + l];
    s16x8 b1 = bp[(ks * 4 + 2 * w + 1) * 64 + l];
    acc0 = __builtin_amdgcn_mfma_f32_32x32x16_bf16(a, b0, acc0, 0, 0, 0);
    acc1 = __builtin_amdgcn_mfma_f32_32x32x16_bf16(a, b1, acc1, 0, 0, 0);
  }

  float s0 = 0.f, q0 = 0.f, s1 = 0.f, q1 = 0.f;
  int f0c = (2 * w) * 32 + m, f1c = (2 * w + 1) * 32 + m;
#pragma unroll
  for (int r = 0; r < 16; r++) {
    int n = (r & 3) + ((r >> 2) << 3) + (kg << 2);
    float v0 = acc0[r], v1 = acc1[r];
    z[(size_t)(n0 + n) * 128 + f0c] = v0;
    z[(size_t)(n0 + n) * 128 + f1c] = v1;
    s0 += v0; q0 += v0 * v0; s1 += v1; q1 += v1 * v1;
  }
  s0 += __shfl_xor(s0, 32); q0 += __shfl_xor(q0, 32);
  s1 += __shfl_xor(s1, 32); q1 += __shfl_xor(q1, 32);
  if (l < 32) {
    size_t base = (size_t)blockIdx.x * 256;
    part[base + w * 64 + m] = s0;
    part[base + w * 64 + 32 + m] = s1;
    part[base + 128 + w * 64 + m] = q0;
    part[base + 128 + w * 64 + 32 + m] = q1;
  }
}

// ---------------------------------------------------------------------------
__global__ __launch_bounds__(256) void kFC2Arc(
    const float* __restrict__ z, const float* __restrict__ s6,
    const float* __restrict__ lg1, const float* __restrict__ lb1,
    const float* __restrict__ pl1, const float* __restrict__ lw2,
    const float* __restrict__ lb2, const float* __restrict__ aw,
    const int* __restrict__ labels, float* __restrict__ out,
    float* __restrict__ lpart) {
  __shared__ float scz[128], shz[128], w2a[128], w2b[128];
  __shared__ float awl[20];
  __shared__ float lred[4];
  int tid = threadIdx.x;
  if (tid < 128) {
    const float invM = 1.0f / 4096.0f;
    float mu = s6[tid] * invM;
    float va = fmaxf(s6[128 + tid] * invM - mu * mu, 0.0f);
    float iv = rsqrtf(va + 1e-5f);
    float sc = lg1[tid] * iv;
    scz[tid] = sc;
    shz[tid] = lb1[tid] - mu * sc;
    w2a[tid] = lw2[tid];
    w2b[tid] = lw2[128 + tid];
  }
  if (tid < 20) awl[tid] = aw[tid];
  __syncthreads();
  float al = *pl1;
  int n = blockIdx.x * 256 + tid;
  const float4* zr = (const float4*)(z + (size_t)n * 128);
  float f0 = lb2[0], f1 = lb2[1];
#pragma unroll
  for (int kb = 0; kb < 32; kb++) {
    float4 v = zr[kb];
    float hv[4] = {v.x, v.y, v.z, v.w};
#pragma unroll
    for (int u = 0; u < 4; u++) {
      int k = kb * 4 + u;
      float h = fmaf(hv[u], scz[k], shz[k]);
      h = h > 0.f ? h : al * h;
      f0 = fmaf(h, w2a[k], f0);
      f1 = fmaf(h, w2b[k], f1);
    }
  }
  out[(size_t)n * 2] = f0;
  out[(size_t)n * 2 + 1] = f1;
  float nrm = sqrtf(fmaxf(f0 * f0 + f1 * f1, 1e-30f));
  float xn0 = f0 / nrm, xn1 = f1 / nrm;
  int lab = labels[n];
  float wv[10];
  float m64 = -3.4e38f;
#pragma unroll
  for (int j = 0; j < 10; j++) {
    float w = xn0 * awl[2 * j] + xn1 * awl[2 * j + 1];
    wv[j] = w;
    out[8192 + (size_t)n * 10 + j] = w;
    m64 = fmaxf(m64, 64.0f * w);
  }
  float tgt = wv[0];
#pragma unroll
  for (int j = 1; j < 10; j++) if (j == lab) tgt = wv[j];
  if (lab == 0) tgt = wv[0];
  const float CLO = (float)(-1.0 + 1e-7);
  const float CHI = (float)(1.0 - 1e-7);
  float t = fminf(fmaxf(tgt, CLO), CHI);
  float num = 64.0f * (t * 0.87758256189037276f - 0.47942553860420301f * sqrtf(fmaxf(1.0f - t * t, 0.0f)));
  float L = fmaxf(num, m64);
  float dsum = expf(num - L) - expf(64.0f * tgt - L);
#pragma unroll
  for (int j = 0; j < 10; j++) dsum += expf(64.0f * wv[j] - L);
  dsum = fmaxf(dsum, 1e-30f);
  float li = num - (L + logf(dsum));
#pragma unroll
  for (int off = 32; off; off >>= 1) li += __shfl_down(li, off);
  if ((tid & 63) == 0) lred[tid >> 6] = li;
  __syncthreads();
  if (tid == 0) lpart[blockIdx.x] = lred[0] + lred[1] + lred[2] + lred[3];
}

__global__ void kFinal(const float* __restrict__ lpart, float* __restrict__ out) {
  int tid = threadIdx.x;
  float v = (tid < 16) ? lpart[tid] : 0.f;
#pragma unroll
  for (int off = 8; off; off >>= 1) v += __shfl_down(v, off);
  if (tid == 0) out[49152] = -v * (1.0f / 4096.0f);
}

// ---------------------------------------------------------------------------
extern "C" void kernel_launch(void* const* d_in, const int* in_sizes, int n_in,
                              void* d_out, int out_size, void* d_ws, size_t ws_size,
                              hipStream_t stream) {
  const float* x   = (const float*)d_in[0];
  const int* labels = (const int*)d_in[1];
  const float* cw0 = (const float*)d_in[2];
  const float* bg0 = (const float*)d_in[3];
  const float* bb0 = (const float*)d_in[4];
  const float* pa0 = (const float*)d_in[5];
  const float* cw1 = (const float*)d_in[6];
  const float* bg1 = (const float*)d_in[7];
  const float* bb1 = (const float*)d_in[8];
  const float* pa1 = (const float*)d_in[9];
  const float* cw2 = (const float*)d_in[10];
  const float* bg2 = (const float*)d_in[11];
  const float* bb2 = (const float*)d_in[12];
  const float* pa2 = (const float*)d_in[13];
  const float* cw3 = (const float*)d_in[14];
  const float* bg3 = (const float*)d_in[15];
  const float* bb3 = (const float*)d_in[16];
  const float* pa3 = (const float*)d_in[17];
  const float* cw4 = (const float*)d_in[18];
  const float* bg4 = (const float*)d_in[19];
  const float* bb4 = (const float*)d_in[20];
  const float* pa4 = (const float*)d_in[21];
  const float* cw5 = (const float*)d_in[22];
  const float* bg5 = (const float*)d_in[23];
  const float* bb5 = (const float*)d_in[24];
  const float* pa5 = (const float*)d_in[25];
  const float* lw1 = (const float*)d_in[26];
  const float* lg1 = (const float*)d_in[27];
  const float* lb1 = (const float*)d_in[28];
  const float* pl1 = (const float*)d_in[29];
  const float* lw2 = (const float*)d_in[30];
  const float* lb2 = (const float*)d_in[31];
  const float* aw  = (const float*)d_in[32];
  float* out = (float*)d_out;
  float* ws = (float*)d_ws;

  float* PX = ws;                    // 1024
  float* SX = ws + 1024;             // 2
  float* S1 = ws + 1040;             // 128
  float* S2 = ws + 1168;             // 64
  float* S3 = ws + 1232;             // 128
  float* S4 = ws + 1360;             // 64
  float* S5 = ws + 1424;             // 128
  float* S6 = ws + 1552;             // 256
  float* LP = ws + 1808;             // 16
  float* P1 = ws + 2048;             // [4096][128]
  float* P2 = P1 + 524288;           // [2704][64]
  float* P3 = P2 + 173056;           // [4096][128]
  float* P4 = P3 + 524288;           // [576][64]
  float* P5 = P4 + 36864;            // [4096][128]
  float* P6 = P1;                    // [128][256] — aliases dead P1
  unsigned short* Y1 = (unsigned short*)(ws + (size_t)2097152);  // [4096][169][64] bf16
  unsigned short* Y2 = Y1 + (size_t)44302336;  // [4096][169][32] bf16
  unsigned short* Y3 = Y2 + (size_t)22151168;  // [4096][36][64] bf16
  unsigned short* Y4 = Y3 + (size_t)9437184;   // [4096][36][32] bf16
  float* Y5 = (float*)(Y4 + (size_t)4718592);  // [4096][1024] fp32 k-order
  float* Z  = Y5 + (size_t)4194304;  // [4096][128]
  float* WF = Z + 524288;            // conv1 weight frags
  float* WFL = WF + 16384;           // lw1 frags (256 KB)
  float* WF3 = WFL + 65536;          // conv3 weight frags

  kPrepW<<<1, 256, 0, stream>>>(cw1, (unsigned short*)WF);
  kPrepW3<<<1, 256, 0, stream>>>(cw3, (unsigned short*)WF3);
  kPrepLW<<<16, 256, 0, stream>>>(lw1, (unsigned short*)WFL);
  kRedX<<<512, 256, 0, stream>>>(x, PX);
  kRedPart<<<2, 256, 0, stream>>>(PX, SX, 512, 2);
  kConv1<<<4096, 256, 0, stream>>>(x, cw0, bg0, bb0, pa0, (const unsigned short*)WF, SX, Y1, P1);
  kRedPart<<<128, 256, 0, stream>>>(P1, S1, 4096, 128);
  kConv1x1b<<<2704, 256, 0, stream>>>(cw2, bg1, bb1, pa1, S1, 1.0f / 692224.0f, Y1, Y2, P2);
  kRedPart<<<64, 256, 0, stream>>>(P2, S2, 2704, 64);
  kConv3m<<<4096, 256, 0, stream>>>((const unsigned short*)WF3, bg2, bb2, pa2, S2, Y2, Y3, P3);
  kRedPart<<<128, 256, 0, stream>>>(P3, S3, 4096, 128);
  kConv1x1b<<<576, 256, 0, stream>>>(cw4, bg3, bb3, pa3, S3, 1.0f / 147456.0f, Y3, Y4, P4);
  kRedPart<<<64, 256, 0, stream>>>(P4, S4, 576, 64);
  kConv5<<<4096, 64, 0, stream>>>(cw5, bg4, bb4, pa4, S4, Y4, Y5, P5);
  kRedPart<<<128, 256, 0, stream>>>(P5, S5, 4096, 128);
  kFC1m<<<128, 128, 0, stream>>>((const unsigned short*)WFL, bg5, bb5, pa5, S5, Y5, Z, P6);
  kRedPart<<<256, 256, 0, stream>>>(P6, S6, 128, 256);
  kFC2Arc<<<16, 256, 0, stream>>>(Z, S6, lg1, lb1, pl1, lw2, lb2, aw, labels, out, LP);
  kFinal<<<1, 64, 0, stream>>>(LP, out);
}

// Round 8
// 284.023 us; speedup vs baseline: 4.6479x; 1.3380x over previous
//
#include <hip/hip_runtime.h>
#include <math.h>

// ---------------------------------------------------------------------------
// R8: 1x1 convs (conv2, conv4) rewritten as bf16 MFMA GEMM [R,64]@[64,32]:
//   kConv1x1m: 256 thr / 4 waves, 128 rows per block staged bf16 in LDS
//   (kFC1m's verified XOR swizzle), 4 MFMAs per wave, stats from registers.
//   Weight B-frags prepped once by kPrepW1x1 (4 frags, 4KB).
// Removes the per-thread broadcast weight LDS storm (512 ds_read_b128/thread)
// that left R7's kConv1x1b LDS-BW-bound at 113us.
// Everything else identical to the passing R7 build.
// ---------------------------------------------------------------------------

typedef __attribute__((ext_vector_type(8))) short s16x8;
typedef __attribute__((ext_vector_type(16))) float f32x16;

__device__ __forceinline__ unsigned short f2bf(float f) {
  union { float f; unsigned int u; } v; v.f = f;
  unsigned int r = (v.u + 0x7FFFu + ((v.u >> 16) & 1u)) >> 16;
  return (unsigned short)r;
}
__device__ __forceinline__ float bf2f(unsigned short h) {
  union { unsigned int u; float f; } t; t.u = ((unsigned int)h) << 16; return t.f;
}

__global__ __launch_bounds__(256) void kRedX(const float* __restrict__ x,
                                             float* __restrict__ part) {
  int tid = threadIdx.x;
  int b = blockIdx.x;
  const float4* x4 = (const float4*)x;
  float s = 0.f, q = 0.f;
  for (size_t i = (size_t)b * 256 + tid; i < 802816; i += (size_t)512 * 256) {
    float4 v = x4[i];
    s += v.x + v.y + v.z + v.w;
    q += v.x * v.x + v.y * v.y + v.z * v.z + v.w * v.w;
  }
#pragma unroll
  for (int off = 32; off; off >>= 1) {
    s += __shfl_down(s, off);
    q += __shfl_down(q, off);
  }
  __shared__ float ls[4][2];
  int w = tid >> 6;
  if ((tid & 63) == 0) { ls[w][0] = s; ls[w][1] = q; }
  __syncthreads();
  if (tid == 0) {
    part[b * 2]     = ls[0][0] + ls[1][0] + ls[2][0] + ls[3][0];
    part[b * 2 + 1] = ls[0][1] + ls[1][1] + ls[2][1] + ls[3][1];
  }
}

__global__ __launch_bounds__(256) void kRedPart(const float* __restrict__ part,
                                                float* __restrict__ outp, int nb, int C2) {
  int slot = blockIdx.x;
  int tid = threadIdx.x;
  float s = 0.f;
  for (int i = tid; i < nb; i += 256) s += part[(size_t)i * C2 + slot];
#pragma unroll
  for (int off = 32; off; off >>= 1) s += __shfl_down(s, off);
  __shared__ float ls[4];
  if ((tid & 63) == 0) ls[tid >> 6] = s;
  __syncthreads();
  if (tid == 0) outp[slot] = ls[0] + ls[1] + ls[2] + ls[3];
}

// ---------------------------------------------------------------------------
__global__ __launch_bounds__(256) void kPrepW(const float* __restrict__ cw1,
                                              unsigned short* __restrict__ wf) {
  int tid = threadIdx.x;
  int lane = tid & 63, fb = tid >> 6;
  int m = lane & 31, kg = lane >> 5;
  for (int pass = 0; pass < 9; pass++) {
    int f = pass * 4 + fb;
    int tap = f >> 2, rem = f & 3, kt = rem >> 1, nt = rem & 1;
    int o = nt * 32 + m;
    int kb = kt * 16 + kg * 8;
    union { s16x8 v; unsigned short e[8]; } u;
#pragma unroll
    for (int j = 0; j < 8; j++)
      u.e[j] = f2bf(cw1[(size_t)o * 288 + (size_t)(kb + j) * 9 + tap]);
    ((s16x8*)wf)[f * 64 + lane] = u.v;
  }
}

__global__ __launch_bounds__(256) void kPrepW3(const float* __restrict__ cw3,
                                               unsigned short* __restrict__ wf3) {
  int tid = threadIdx.x;
  int lane = tid & 63, fq = tid >> 6;
  int m = lane & 31, kg = lane >> 5;
  for (int pass = 0; pass < 9; pass++) {
    int f = pass * 4 + fq;  // 0..35
    int s = f >> 1, nt = f & 1;
    int tap = s >> 1;
    int o = nt * 32 + m;
    int c0 = (s & 1) * 16 + kg * 8;
    union { s16x8 v; unsigned short e[8]; } u;
#pragma unroll
    for (int j = 0; j < 8; j++)
      u.e[j] = f2bf(cw3[(size_t)o * 288 + (size_t)(c0 + j) * 9 + tap]);
    ((s16x8*)wf3)[f * 64 + lane] = u.v;
  }
}

// kPrepW1x1: [32o][64c] -> 4 B-frags: frag ks, lane l: B[k=ks*16+(l>>5)*8+j][o=l&31]
__global__ __launch_bounds__(256) void kPrepW1x1(const float* __restrict__ wgt,
                                                 unsigned short* __restrict__ wfb) {
  int tid = threadIdx.x;
  int l = tid & 63, ks = tid >> 6;
  int o = l & 31, kg = l >> 5;
  union { s16x8 v; unsigned short e[8]; } u;
#pragma unroll
  for (int j = 0; j < 8; j++) {
    int c = ks * 16 + kg * 8 + j;
    u.e[j] = f2bf(wgt[o * 64 + c]);
  }
  ((s16x8*)wfb)[ks * 64 + l] = u.v;
}

// ---------------------------------------------------------------------------
// kConv1 (MFMA): y1 out bf16.
// ---------------------------------------------------------------------------
__global__ __launch_bounds__(256, 2) void kConv1(
    const float* __restrict__ x, const float* __restrict__ cw0,
    const float* __restrict__ bg0, const float* __restrict__ bb0,
    const float* __restrict__ pa0, const unsigned short* __restrict__ wf,
    const float* __restrict__ sx, unsigned short* __restrict__ y1b,
    float* __restrict__ part) {
  __shared__ __align__(16) unsigned short h0t[25088];
  __shared__ __align__(16) float xs[784];
  __shared__ float s0[32], t0[32];
  __shared__ float sS[4][32], sQ[4][32];
  int tid = threadIdx.x;
  int n = blockIdx.x;
  int l = tid & 63, w = tid >> 6;
  int nt = w & 1, mh = w >> 1;
  int m = l & 31, kg = l >> 5;

  s16x8 bfr[9][2];
  const s16x8* wfp = (const s16x8*)wf;
#pragma unroll
  for (int tap = 0; tap < 9; tap++)
#pragma unroll
    for (int kt = 0; kt < 2; kt++)
      bfr[tap][kt] = wfp[(tap * 4 + kt * 2 + nt) * 64 + l];

  if (tid < 196) ((float4*)xs)[tid] = ((const float4*)(x + (size_t)n * 784))[tid];
  if (tid < 32) {
    const float invM = 1.0f / (4096.0f * 784.0f);
    float mux = sx[0] * invM;
    float varx = fmaxf(sx[1] * invM - mux * mux, 0.0f);
    float w0 = cw0[tid];
    float inv = rsqrtf(w0 * w0 * varx + 1e-5f);
    float sc = w0 * bg0[tid] * inv;
    s0[tid] = sc;
    t0[tid] = bb0[tid] - mux * sc;
  }
  __syncthreads();

  float a0p = *pa0;
  int g = tid & 3;
  float sg[8], tg[8];
#pragma unroll
  for (int j = 0; j < 8; j++) { sg[j] = s0[g * 8 + j]; tg[j] = t0[g * 8 + j]; }
  char* h0b = (char*)h0t;
  int koffW = g * 16;
  for (int t = 0; t < 13; t++) {
    int p = (tid >> 2) + t * 64;
    if (p < 784) {
      float xv = xs[p];
      union { s16x8 v; unsigned short e[8]; } u;
#pragma unroll
      for (int j = 0; j < 8; j++) {
        float v = fmaf(xv, sg[j], tg[j]);
        v = v > 0.f ? v : a0p * v;
        u.e[j] = f2bf(v);
      }
      int ad = ((p << 6) + koffW) ^ (((p >> 1) & 7) << 4);
      *(s16x8*)(h0b + ad) = u.v;
    }
  }
  __syncthreads();

  int pixb[3];
#pragma unroll
  for (int mt = 0; mt < 3; mt++) {
    int p = (mh * 3 + mt) * 32 + m;
    p = p > 168 ? 168 : p;
    pixb[mt] = (p / 13) * 56 + (p % 13) * 2;
  }
  int koffA = kg * 16;

#define Z16 {0.f,0.f,0.f,0.f, 0.f,0.f,0.f,0.f, 0.f,0.f,0.f,0.f, 0.f,0.f,0.f,0.f}
  f32x16 acc0 = Z16, acc1 = Z16, acc2 = Z16;

#define MT_STEP(ACC, MTL) { int pb = pixb[MTL]; \
  _Pragma("unroll") for (int tap = 0; tap < 9; tap++) { \
    int pix = pb + (tap / 3) * 28 + (tap % 3); \
    int ad = ((pix << 6) + koffA) ^ (((pix >> 1) & 7) << 4); \
    s16x8 a0 = *(const s16x8*)(h0b + ad); \
    s16x8 a1 = *(const s16x8*)(h0b + (ad ^ 32)); \
    ACC = __builtin_amdgcn_mfma_f32_32x32x16_bf16(a0, bfr[tap][0], ACC, 0, 0, 0); \
    ACC = __builtin_amdgcn_mfma_f32_32x32x16_bf16(a1, bfr[tap][1], ACC, 0, 0, 0); \
  } }

  MT_STEP(acc0, 0)
  MT_STEP(acc1, 1)
  MT_STEP(acc2, 2)
#undef MT_STEP

  float s = 0.f, q = 0.f;
  int och = nt * 32 + m;
#define ST_MT(ACC, MTL) { int pbase = (mh * 3 + MTL) * 32 + (kg << 2); \
  _Pragma("unroll") for (int r = 0; r < 16; r++) { \
    int p = pbase + (r & 3) + ((r >> 2) << 3); \
    if (p < 169) { float v = ACC[r]; \
      y1b[((size_t)n * 169 + p) * 64 + och] = f2bf(v); s += v; q += v * v; } } }

  ST_MT(acc0, 0)
  ST_MT(acc1, 1)
  ST_MT(acc2, 2)
#undef ST_MT

  s += __shfl_xor(s, 32);
  q += __shfl_xor(q, 32);
  if (l < 32) { sS[w][l] = s; sQ[w][l] = q; }
  __syncthreads();
  if (tid < 64) {
    int o = tid, wv = o >> 5;
    part[(size_t)n * 128 + o] = sS[wv][o & 31] + sS[wv + 2][o & 31];
  } else if (tid < 128) {
    int o = tid - 64, wv = o >> 5;
    part[(size_t)n * 128 + 64 + o] = sQ[wv][o & 31] + sQ[wv + 2][o & 31];
  }
}

// ---------------------------------------------------------------------------
// kConv1x1m: MFMA GEMM [R,64] @ [64,32] -> compact bf16 [R,32].
// 256 thr / 4 waves; block = 128 rows; wave = 32-row M-tile; 4 k-steps.
// part per block: [32 sums][32 sq].
// ---------------------------------------------------------------------------
__global__ __launch_bounds__(256, 4) void kConv1x1m(
    const unsigned short* __restrict__ wfb, const float* __restrict__ g,
    const float* __restrict__ b, const float* __restrict__ pa,
    const float* __restrict__ stats, float invM,
    const unsigned short* __restrict__ in, unsigned short* __restrict__ outb,
    float* __restrict__ part) {
  __shared__ __align__(16) unsigned short hs[128 * 64];  // 16 KB
  __shared__ float scs[64], shs[64];
  __shared__ float sS[4][32], sQ[4][32];
  int tid = threadIdx.x;
  size_t r0 = (size_t)blockIdx.x * 128;
  int l = tid & 63, w = tid >> 6;
  int m = l & 31, kg = l >> 5;

  s16x8 bfr[4];
  const s16x8* bp = (const s16x8*)wfb;
#pragma unroll
  for (int ks = 0; ks < 4; ks++) bfr[ks] = bp[ks * 64 + l];

  if (tid < 64) {
    float mu = stats[tid] * invM;
    float va = fmaxf(stats[64 + tid] * invM - mu * mu, 0.0f);
    float iv = rsqrtf(va + 1e-5f);
    float sc = g[tid] * iv;
    scs[tid] = sc;
    shs[tid] = b[tid] - mu * sc;
  }
  __syncthreads();
  float al = *pa;
  char* hb = (char*)hs;
#pragma unroll
  for (int i = 0; i < 4; i++) {
    int e = tid + i * 256;            // 0..1023 = 128 rows x 8 segs
    int row = e >> 3, seg = e & 7;
    union { s16x8 v; unsigned short e8[8]; } u, o8;
    u.v = *(const s16x8*)(in + (r0 + row) * 64 + seg * 8);
#pragma unroll
    for (int j = 0; j < 8; j++) {
      int c = seg * 8 + j;
      float h = fmaf(bf2f(u.e8[j]), scs[c], shs[c]);
      h = h > 0.f ? h : al * h;
      o8.e8[j] = f2bf(h);
    }
    int ad = (row * 128 + seg * 16) ^ ((row & 7) << 4);
    *(s16x8*)(hb + ad) = o8.v;
  }
  __syncthreads();

#define Z16 {0.f,0.f,0.f,0.f, 0.f,0.f,0.f,0.f, 0.f,0.f,0.f,0.f, 0.f,0.f,0.f,0.f}
  f32x16 acc = Z16;
#undef Z16
  int rloc = w * 32 + m;
  int abase = (rloc * 128 + kg * 16) ^ ((rloc & 7) << 4);
#pragma unroll
  for (int ks = 0; ks < 4; ks++) {
    s16x8 a = *(const s16x8*)(hb + (abase ^ (ks * 32)));
    acc = __builtin_amdgcn_mfma_f32_32x32x16_bf16(a, bfr[ks], acc, 0, 0, 0);
  }

  float ss = 0.f, qq = 0.f;
#pragma unroll
  for (int rr = 0; rr < 16; rr++) {
    int rowt = (rr & 3) + ((rr >> 2) << 3) + (kg << 2);
    float v = acc[rr];
    outb[(r0 + (size_t)w * 32 + rowt) * 32 + m] = f2bf(v);
    ss += v; qq += v * v;
  }
  ss += __shfl_xor(ss, 32);
  qq += __shfl_xor(qq, 32);
  if (l < 32) { sS[w][l] = ss; sQ[w][l] = qq; }
  __syncthreads();
  if (tid < 32) {
    part[(size_t)blockIdx.x * 64 + tid] = sS[0][tid] + sS[1][tid] + sS[2][tid] + sS[3][tid];
  } else if (tid < 64) {
    int o = tid - 32;
    part[(size_t)blockIdx.x * 64 + 32 + o] = sQ[0][o] + sQ[1][o] + sQ[2][o] + sQ[3][o];
  }
}

// ---------------------------------------------------------------------------
// kConv3m (MFMA): input compact bf16 y2 [169][32]; output bf16 y3 [36][64].
// ---------------------------------------------------------------------------
__global__ __launch_bounds__(256, 3) void kConv3m(
    const unsigned short* __restrict__ wf3, const float* __restrict__ g,
    const float* __restrict__ b, const float* __restrict__ pa,
    const float* __restrict__ stats, const unsigned short* __restrict__ in,
    unsigned short* __restrict__ outb, float* __restrict__ part) {
  __shared__ __align__(16) unsigned short h2t[169 * 32];  // 10,816 B
  __shared__ float scs[32], shs[32];
  __shared__ float sS[4][32], sQ[4][32];
  int tid = threadIdx.x;
  int n = blockIdx.x;
  int l = tid & 63, w = tid >> 6;
  int nt = w & 1, mt = w >> 1;
  int m = l & 31, kg = l >> 5;

  s16x8 bfr[18];
  const s16x8* wfp = (const s16x8*)wf3;
#pragma unroll
  for (int s = 0; s < 18; s++) bfr[s] = wfp[(s * 2 + nt) * 64 + l];

  if (tid < 32) {
    const float invM = 1.0f / 692224.0f;
    float mu = stats[tid] * invM;
    float va = fmaxf(stats[32 + tid] * invM - mu * mu, 0.0f);
    float iv = rsqrtf(va + 1e-5f);
    float sc = g[tid] * iv;
    scs[tid] = sc;
    shs[tid] = b[tid] - mu * sc;
  }
  __syncthreads();
  float al = *pa;
  char* hb = (char*)h2t;
  for (int e = tid; e < 676; e += 256) {
    int p = e >> 2, q = e & 3;
    union { s16x8 v; unsigned short e8[8]; } u, o8;
    u.v = ((const s16x8*)(in + ((size_t)n * 169 + p) * 32))[q];
#pragma unroll
    for (int j = 0; j < 8; j++) {
      int c = q * 8 + j;
      float h = fmaf(bf2f(u.e8[j]), scs[c], shs[c]);
      h = h > 0.f ? h : al * h;
      o8.e8[j] = f2bf(h);
    }
    int ad = ((p << 6) + q * 16) ^ (((p >> 1) & 7) << 4);
    *(s16x8*)(hb + ad) = o8.v;
  }
  __syncthreads();

  int p = mt * 32 + m;
  p = p > 35 ? 35 : p;
  int pixb = (p / 6) * 26 + (p % 6) * 2;  // (2i)*13 + 2j

#define Z16 {0.f,0.f,0.f,0.f, 0.f,0.f,0.f,0.f, 0.f,0.f,0.f,0.f, 0.f,0.f,0.f,0.f}
  f32x16 acc = Z16;
#undef Z16
#pragma unroll
  for (int s = 0; s < 18; s++) {
    int tap = s >> 1;
    int pix = pixb + (tap / 3) * 13 + (tap % 3);
    int ad = ((pix << 6) + (s & 1) * 32 + kg * 16) ^ (((pix >> 1) & 7) << 4);
    s16x8 a = *(const s16x8*)(hb + ad);
    acc = __builtin_amdgcn_mfma_f32_32x32x16_bf16(a, bfr[s], acc, 0, 0, 0);
  }

  float ss = 0.f, qq = 0.f;
  int och = nt * 32 + m;
#pragma unroll
  for (int r = 0; r < 16; r++) {
    int row = (r & 3) + ((r >> 2) << 3) + (kg << 2);
    int pp = mt * 32 + row;
    if (pp < 36) {
      float v = acc[r];
      outb[((size_t)n * 36 + pp) * 64 + och] = f2bf(v);
      ss += v; qq += v * v;
    }
  }
  ss += __shfl_xor(ss, 32);
  qq += __shfl_xor(qq, 32);
  if (l < 32) { sS[w][l] = ss; sQ[w][l] = qq; }
  __syncthreads();
  if (tid < 64) {
    int o = tid, wv = o >> 5;
    part[(size_t)n * 128 + o] = sS[wv][o & 31] + sS[wv + 2][o & 31];
  } else if (tid < 128) {
    int o = tid - 64, wv = o >> 5;
    part[(size_t)n * 128 + 64 + o] = sQ[wv][o & 31] + sQ[wv + 2][o & 31];
  }
}

// ---------------------------------------------------------------------------
// kConv5: input compact bf16 y4 [36][32]; output y5 fp32 k-order [n][o*16+p].
// ---------------------------------------------------------------------------
__global__ __launch_bounds__(64) void kConv5(
    const float* __restrict__ wgt, const float* __restrict__ g,
    const float* __restrict__ b, const float* __restrict__ pa,
    const float* __restrict__ stats, const unsigned short* __restrict__ in,
    float* __restrict__ outb, float* __restrict__ part) {
  __shared__ float h4[32][6][8];
  __shared__ float scs[32], shs[32];
  int tid = threadIdx.x;
  int n = blockIdx.x;
  if (tid < 32) {
    const float invM = 1.0f / 147456.0f;
    float mu = stats[tid] * invM;
    float va = fmaxf(stats[32 + tid] * invM - mu * mu, 0.0f);
    float iv = rsqrtf(va + 1e-5f);
    float sc = g[tid] * iv;
    scs[tid] = sc;
    shs[tid] = b[tid] - mu * sc;
  }
  __syncthreads();
  float al = *pa;
  for (int e = tid; e < 144; e += 64) {
    int p = e >> 2, q = e & 3;
    union { s16x8 v; unsigned short e8[8]; } u;
    u.v = ((const s16x8*)(in + ((size_t)n * 36 + p) * 32))[q];
#pragma unroll
    for (int j = 0; j < 8; j++) {
      int c = q * 8 + j;
      float v = fmaf(bf2f(u.e8[j]), scs[c], shs[c]);
      v = v > 0.f ? v : al * v;
      h4[c][p / 6][p % 6] = v;
    }
  }
  __syncthreads();
  int o = tid;
  float acc[16];
#pragma unroll
  for (int p = 0; p < 16; p++) acc[p] = 0.f;
  const float* wb = wgt + (size_t)o * 288;
  for (int c = 0; c < 32; c++) {
    float wr[9];
#pragma unroll
    for (int k = 0; k < 9; k++) wr[k] = wb[c * 9 + k];
#pragma unroll
    for (int ih = 0; ih < 6; ih++) {
      float4 rq[2];
      rq[0] = ((const float4*)&h4[c][ih][0])[0];
      rq[1] = ((const float4*)&h4[c][ih][0])[1];
#pragma unroll
      for (int kh = 0; kh < 3; kh++) {
        int i = ih - kh;
        if (i >= 0 && i < 4) {
#pragma unroll
          for (int kw = 0; kw < 3; kw++) {
            float wv = wr[kh * 3 + kw];
#pragma unroll
            for (int j = 0; j < 4; j++)
              acc[i * 4 + j] = fmaf(((const float*)rq)[j + kw], wv, acc[i * 4 + j]);
          }
        }
      }
    }
  }
  float s = 0.f, q = 0.f;
  float* dst = outb + (size_t)n * 1024 + o * 16;
#pragma unroll
  for (int pb = 0; pb < 4; pb++) {
    float4 st = {acc[pb * 4], acc[pb * 4 + 1], acc[pb * 4 + 2], acc[pb * 4 + 3]};
    ((float4*)dst)[pb] = st;
#pragma unroll
    for (int u = 0; u < 4; u++) { float v = acc[pb * 4 + u]; s += v; q += v * v; }
  }
  part[(size_t)n * 128 + o] = s;
  part[(size_t)n * 128 + 64 + o] = q;
}

// ---------------------------------------------------------------------------
__global__ __launch_bounds__(256) void kPrepLW(const float* __restrict__ lw1,
                                               unsigned short* __restrict__ wfl) {
  int tid = threadIdx.x;
  int lane = tid & 63, fq = tid >> 6;
  int m = lane & 31, kg = lane >> 5;
  for (int pp = 0; pp < 4; pp++) {
    int f_idx = (blockIdx.x * 4 + pp) * 4 + fq;  // 0..255
    int ks = f_idx >> 2, nt = f_idx & 3;
    int f = nt * 32 + m;
    int kb = ks * 16 + kg * 8;
    const float4* src = (const float4*)(lw1 + (size_t)f * 1024 + kb);
    float4 v0 = src[0], v1 = src[1];
    float t[8] = {v0.x, v0.y, v0.z, v0.w, v1.x, v1.y, v1.z, v1.w};
    union { s16x8 v; unsigned short e[8]; } u;
#pragma unroll
    for (int j = 0; j < 8; j++) u.e[j] = f2bf(t[j]);
    ((s16x8*)wfl)[f_idx * 64 + lane] = u.v;
  }
}

// ---------------------------------------------------------------------------
__global__ __launch_bounds__(128) void kFC1m(
    const unsigned short* __restrict__ wfl, const float* __restrict__ g,
    const float* __restrict__ b, const float* __restrict__ pa,
    const float* __restrict__ stats, const float* __restrict__ y5,
    float* __restrict__ z, float* __restrict__ part) {
  __shared__ __align__(16) unsigned short hs[32 * 1024];  // 64 KB
  __shared__ float scs[64], shs[64];
  int tid = threadIdx.x;
  int n0 = blockIdx.x * 32;
  if (tid < 64) {
    const float invM = 1.0f / 65536.0f;
    float mu = stats[tid] * invM;
    float va = fmaxf(stats[64 + tid] * invM - mu * mu, 0.0f);
    float iv = rsqrtf(va + 1e-5f);
    float sc = g[tid] * iv;
    scs[tid] = sc;
    shs[tid] = b[tid] - mu * sc;
  }
  __syncthreads();
  float al = *pa;
  char* hb = (char*)hs;
  for (int i = 0; i < 32; i++) {
    int sgi = tid + i * 128;
    int nn = sgi >> 7, k8 = sgi & 127;
    int c = k8 >> 1;
    float sc = scs[c], sh = shs[c];
    const float4* src = (const float4*)(y5 + (size_t)(n0 + nn) * 1024 + k8 * 8);
    float4 v0 = src[0], v1 = src[1];
    float t[8] = {v0.x, v0.y, v0.z, v0.w, v1.x, v1.y, v1.z, v1.w};
    union { s16x8 v; unsigned short e[8]; } u;
#pragma unroll
    for (int j = 0; j < 8; j++) {
      float h = fmaf(t[j], sc, sh);
      h = h > 0.f ? h : al * h;
      u.e[j] = f2bf(h);
    }
    int ad = (nn * 2048 + k8 * 16) ^ ((nn & 7) << 4);
    *(s16x8*)(hb + ad) = u.v;
  }
  __syncthreads();

  int l = tid & 63, w = tid >> 6;
  int m = l & 31, kg = l >> 5;
#define Z16 {0.f,0.f,0.f,0.f, 0.f,0.f,0.f,0.f, 0.f,0.f,0.f,0.f, 0.f,0.f,0.f,0.f}
  f32x16 acc0 = Z16, acc1 = Z16;
#undef Z16
  const s16x8* bp = (const s16x8*)wfl;
  int abase = (m * 2048 + kg * 16) ^ ((m & 7) << 4);
#pragma unroll 4
  for (int ks = 0; ks < 64; ks++) {
    s16x8 a = *(const s16x8*)(hb + (abase ^ (ks * 32)));
    s16x8 b0 = bp[(ks * 4 + 2 * w + 0) * 64 + l];
    s16x8 b1 = bp[(ks * 4 + 2 * w + 1) * 64 + l];
    acc0 = __builtin_amdgcn_mfma_f32_32x32x16_bf16(a, b0, acc0, 0, 0, 0);
    acc1 = __builtin_amdgcn_mfma_f32_32x32x16_bf16(a, b1, acc1, 0, 0, 0);
  }

  float s0 = 0.f, q0 = 0.f, s1 = 0.f, q1 = 0.f;
  int f0c = (2 * w) * 32 + m, f1c = (2 * w + 1) * 32 + m;
#pragma unroll
  for (int r = 0; r < 16; r++) {
    int n = (r & 3) + ((r >> 2) << 3) + (kg << 2);
    float v0 = acc0[r], v1 = acc1[r];
    z[(size_t)(n0 + n) * 128 + f0c] = v0;
    z[(size_t)(n0 + n) * 128 + f1c] = v1;
    s0 += v0; q0 += v0 * v0; s1 += v1; q1 += v1 * v1;
  }
  s0 += __shfl_xor(s0, 32); q0 += __shfl_xor(q0, 32);
  s1 += __shfl_xor(s1, 32); q1 += __shfl_xor(q1, 32);
  if (l < 32) {
    size_t base = (size_t)blockIdx.x * 256;
    part[base + w * 64 + m] = s0;
    part[base + w * 64 + 32 + m] = s1;
    part[base + 128 + w * 64 + m] = q0;
    part[base + 128 + w * 64 + 32 + m] = q1;
  }
}

// ---------------------------------------------------------------------------
__global__ __launch_bounds__(256) void kFC2Arc(
    const float* __restrict__ z, const float* __restrict__ s6,
    const float* __restrict__ lg1, const float* __restrict__ lb1,
    const float* __restrict__ pl1, const float* __restrict__ lw2,
    const float* __restrict__ lb2, const float* __restrict__ aw,
    const int* __restrict__ labels, float* __restrict__ out,
    float* __restrict__ lpart) {
  __shared__ float scz[128], shz[128], w2a[128], w2b[128];
  __shared__ float awl[20];
  __shared__ float lred[4];
  int tid = threadIdx.x;
  if (tid < 128) {
    const float invM = 1.0f / 4096.0f;
    float mu = s6[tid] * invM;
    float va = fmaxf(s6[128 + tid] * invM - mu * mu, 0.0f);
    float iv = rsqrtf(va + 1e-5f);
    float sc = lg1[tid] * iv;
    scz[tid] = sc;
    shz[tid] = lb1[tid] - mu * sc;
    w2a[tid] = lw2[tid];
    w2b[tid] = lw2[128 + tid];
  }
  if (tid < 20) awl[tid] = aw[tid];
  __syncthreads();
  float al = *pl1;
  int n = blockIdx.x * 256 + tid;
  const float4* zr = (const float4*)(z + (size_t)n * 128);
  float f0 = lb2[0], f1 = lb2[1];
#pragma unroll
  for (int kb = 0; kb < 32; kb++) {
    float4 v = zr[kb];
    float hv[4] = {v.x, v.y, v.z, v.w};
#pragma unroll
    for (int u = 0; u < 4; u++) {
      int k = kb * 4 + u;
      float h = fmaf(hv[u], scz[k], shz[k]);
      h = h > 0.f ? h : al * h;
      f0 = fmaf(h, w2a[k], f0);
      f1 = fmaf(h, w2b[k], f1);
    }
  }
  out[(size_t)n * 2] = f0;
  out[(size_t)n * 2 + 1] = f1;
  float nrm = sqrtf(fmaxf(f0 * f0 + f1 * f1, 1e-30f));
  float xn0 = f0 / nrm, xn1 = f1 / nrm;
  int lab = labels[n];
  float wv[10];
  float m64 = -3.4e38f;
#pragma unroll
  for (int j = 0; j < 10; j++) {
    float w = xn0 * awl[2 * j] + xn1 * awl[2 * j + 1];
    wv[j] = w;
    out[8192 + (size_t)n * 10 + j] = w;
    m64 = fmaxf(m64, 64.0f * w);
  }
  float tgt = wv[0];
#pragma unroll
  for (int j = 1; j < 10; j++) if (j == lab) tgt = wv[j];
  if (lab == 0) tgt = wv[0];
  const float CLO = (float)(-1.0 + 1e-7);
  const float CHI = (float)(1.0 - 1e-7);
  float t = fminf(fmaxf(tgt, CLO), CHI);
  float num = 64.0f * (t * 0.87758256189037276f - 0.47942553860420301f * sqrtf(fmaxf(1.0f - t * t, 0.0f)));
  float L = fmaxf(num, m64);
  float dsum = expf(num - L) - expf(64.0f * tgt - L);
#pragma unroll
  for (int j = 0; j < 10; j++) dsum += expf(64.0f * wv[j] - L);
  dsum = fmaxf(dsum, 1e-30f);
  float li = num - (L + logf(dsum));
#pragma unroll
  for (int off = 32; off; off >>= 1) li += __shfl_down(li, off);
  if ((tid & 63) == 0) lred[tid >> 6] = li;
  __syncthreads();
  if (tid == 0) lpart[blockIdx.x] = lred[0] + lred[1] + lred[2] + lred[3];
}

__global__ void kFinal(const float* __restrict__ lpart, float* __restrict__ out) {
  int tid = threadIdx.x;
  float v = (tid < 16) ? lpart[tid] : 0.f;
#pragma unroll
  for (int off = 8; off; off >>= 1) v += __shfl_down(v, off);
  if (tid == 0) out[49152] = -v * (1.0f / 4096.0f);
}

// ---------------------------------------------------------------------------
extern "C" void kernel_launch(void* const* d_in, const int* in_sizes, int n_in,
                              void* d_out, int out_size, void* d_ws, size_t ws_size,
                              hipStream_t stream) {
  const float* x   = (const float*)d_in[0];
  const int* labels = (const int*)d_in[1];
  const float* cw0 = (const float*)d_in[2];
  const float* bg0 = (const float*)d_in[3];
  const float* bb0 = (const float*)d_in[4];
  const float* pa0 = (const float*)d_in[5];
  const float* cw1 = (const float*)d_in[6];
  const float* bg1 = (const float*)d_in[7];
  const float* bb1 = (const float*)d_in[8];
  const float* pa1 = (const float*)d_in[9];
  const float* cw2 = (const float*)d_in[10];
  const float* bg2 = (const float*)d_in[11];
  const float* bb2 = (const float*)d_in[12];
  const float* pa2 = (const float*)d_in[13];
  const float* cw3 = (const float*)d_in[14];
  const float* bg3 = (const float*)d_in[15];
  const float* bb3 = (const float*)d_in[16];
  const float* pa3 = (const float*)d_in[17];
  const float* cw4 = (const float*)d_in[18];
  const float* bg4 = (const float*)d_in[19];
  const float* bb4 = (const float*)d_in[20];
  const float* pa4 = (const float*)d_in[21];
  const float* cw5 = (const float*)d_in[22];
  const float* bg5 = (const float*)d_in[23];
  const float* bb5 = (const float*)d_in[24];
  const float* pa5 = (const float*)d_in[25];
  const float* lw1 = (const float*)d_in[26];
  const float* lg1 = (const float*)d_in[27];
  const float* lb1 = (const float*)d_in[28];
  const float* pl1 = (const float*)d_in[29];
  const float* lw2 = (const float*)d_in[30];
  const float* lb2 = (const float*)d_in[31];
  const float* aw  = (const float*)d_in[32];
  float* out = (float*)d_out;
  float* ws = (float*)d_ws;

  float* PX = ws;                    // 1024
  float* SX = ws + 1024;             // 2
  float* S1 = ws + 1040;             // 128
  float* S2 = ws + 1168;             // 64
  float* S3 = ws + 1232;             // 128
  float* S4 = ws + 1360;             // 64
  float* S5 = ws + 1424;             // 128
  float* S6 = ws + 1552;             // 256
  float* LP = ws + 1808;             // 16
  float* P1 = ws + 2048;             // [4096][128] = 524288
  float* P2 = P1 + 524288;           // [5408][64] = 346112
  float* P3 = P2 + 346112;           // [4096][128] = 524288
  float* P4 = P3 + 524288;           // [1152][64] = 73728
  float* P5 = P4 + 73728;            // [4096][128] = 524288
  float* P6 = P1;                    // [128][256] — aliases dead P1
  unsigned short* Y1 = (unsigned short*)(ws + (size_t)2097152);  // [4096][169][64] bf16
  unsigned short* Y2 = Y1 + (size_t)44302336;  // [4096][169][32] bf16
  unsigned short* Y3 = Y2 + (size_t)22151168;  // [4096][36][64] bf16
  unsigned short* Y4 = Y3 + (size_t)9437184;   // [4096][36][32] bf16
  float* Y5 = (float*)(Y4 + (size_t)4718592);  // [4096][1024] fp32 k-order
  float* Z  = Y5 + (size_t)4194304;  // [4096][128]
  float* WF = Z + 524288;            // conv1 weight frags
  float* WFL = WF + 16384;           // lw1 frags (256 KB)
  float* WF3 = WFL + 65536;          // conv3 weight frags
  float* WC2 = WF3 + 16384;          // conv2 1x1 frags (4 KB)
  float* WC4 = WC2 + 1024;           // conv4 1x1 frags (4 KB)

  kPrepW<<<1, 256, 0, stream>>>(cw1, (unsigned short*)WF);
  kPrepW3<<<1, 256, 0, stream>>>(cw3, (unsigned short*)WF3);
  kPrepW1x1<<<1, 256, 0, stream>>>(cw2, (unsigned short*)WC2);
  kPrepW1x1<<<1, 256, 0, stream>>>(cw4, (unsigned short*)WC4);
  kPrepLW<<<16, 256, 0, stream>>>(lw1, (unsigned short*)WFL);
  kRedX<<<512, 256, 0, stream>>>(x, PX);
  kRedPart<<<2, 256, 0, stream>>>(PX, SX, 512, 2);
  kConv1<<<4096, 256, 0, stream>>>(x, cw0, bg0, bb0, pa0, (const unsigned short*)WF, SX, Y1, P1);
  kRedPart<<<128, 256, 0, stream>>>(P1, S1, 4096, 128);
  kConv1x1m<<<5408, 256, 0, stream>>>((const unsigned short*)WC2, bg1, bb1, pa1, S1,
                                      1.0f / 692224.0f, Y1, Y2, P2);
  kRedPart<<<64, 256, 0, stream>>>(P2, S2, 5408, 64);
  kConv3m<<<4096, 256, 0, stream>>>((const unsigned short*)WF3, bg2, bb2, pa2, S2, Y2, Y3, P3);
  kRedPart<<<128, 256, 0, stream>>>(P3, S3, 4096, 128);
  kConv1x1m<<<1152, 256, 0, stream>>>((const unsigned short*)WC4, bg3, bb3, pa3, S3,
                                      1.0f / 147456.0f, Y3, Y4, P4);
  kRedPart<<<64, 256, 0, stream>>>(P4, S4, 1152, 64);
  kConv5<<<4096, 64, 0, stream>>>(cw5, bg4, bb4, pa4, S4, Y4, Y5, P5);
  kRedPart<<<128, 256, 0, stream>>>(P5, S5, 4096, 128);
  kFC1m<<<128, 128, 0, stream>>>((const unsigned short*)WFL, bg5, bb5, pa5, S5, Y5, Z, P6);
  kRedPart<<<256, 256, 0, stream>>>(P6, S6, 128, 256);
  kFC2Arc<<<16, 256, 0, stream>>>(Z, S6, lg1, lb1, pl1, lw2, lb2, aw, labels, out, LP);
  kFinal<<<1, 64, 0, stream>>>(LP, out);
}